// Round 18
// baseline (77.624 us; speedup 1.0000x reference)
//
#include <hip/hip_runtime.h>
#include <hip/hip_bf16.h>

// Problem constants (fixed by setup_inputs): B=8, T=2048, D=1024, positions in [0,64).
#define NB 8
#define NT 2048
#define ND 1024
#define CAP 2048

typedef unsigned short ushort_t;
using short8 = __attribute__((ext_vector_type(8))) short;   // 8 bf16 (4 VGPR)
using f32x4  = __attribute__((ext_vector_type(4))) float;   // MFMA accum

__device__ __forceinline__ ushort_t f2bf(float f) {
    __hip_bfloat16 h = __float2bfloat16(f);
    return *reinterpret_cast<ushort_t*>(&h);
}
__device__ __forceinline__ float bf2f(ushort_t u) {
    unsigned int v = ((unsigned int)u) << 16;
    return __int_as_float((int)v);
}

// MFMA operand K-slot mapping for 16x16x32 bf16: k(g,i) = (i>>2)*16+4g+(i&3),
// g = lane>>4. Consistent on A-table (k1) and B-reads (k2/k3) -> any
// permutation error cancels over the reduction axis. C/D: col=lane&15,
// row=4*(lane>>4)+reg [HW-verified]. (Validated: rounds 13-17 absmax.)

// ---------------------------------------------------------------------------
// Workspace layout (byte offsets):
// ---------------------------------------------------------------------------
#define OFF_G2     256
#define OFF_AFH    768
#define OFF_AFL    8960
#define OFF_CNTV   17152
#define OFF_CNTH   19200
#define OFF_INVDEN 21248
#define OFF_GOFF   152320
#define OFF_TOKV   160512
#define OFF_TOKH   4354816
#define OFF_TOKV2  8549120
#define OFF_B1     12743424
#define B1_SLAB    ((size_t)64 * 64 * 1024 * 2)   // 8 MB per batch (bf16)

// Shared kden body: denominator table via LDS-atomic INTEGER histogram
// (deterministic) + two 64x64 mini-matmuls. g table computed locally.
__device__ __forceinline__ void kden_body(
    int kb, const int* __restrict__ posv, const int* __restrict__ posh,
    float* __restrict__ invden, int b0)
{
    int b   = b0 + (kb >> 3);
    int phg = kb & 7;
    int tid = threadIdx.x;

    __shared__ int   hist[64][64];
    __shared__ float g2s[128];
    __shared__ float tmp[64][8];

#pragma unroll
    for (int k = 0; k < 16; k++) ((int*)hist)[tid + (k << 8)] = 0;
    if (tid < 128) {
        int k = tid, r = k - 63;
        g2s[tid] = (k < 127) ? expf(-(float)(r * r) * (1.0f / 512.0f)) : 0.0f;
    }
    __syncthreads();
#pragma unroll
    for (int k = 0; k < 8; k++) {
        int t = (k << 8) + tid;
        atomicAdd(&hist[posv[b * NT + t]][posh[b * NT + t]], 1);
    }
    __syncthreads();
#pragma unroll
    for (int c = 0; c < 2; c++) {
        int cell = (c << 8) + tid;
        int j    = cell >> 3;
        int phl  = cell & 7;
        int ph   = (phg << 3) + phl;
        float s = 0.f;
        for (int k = 0; k < 64; k++)
            s += (float)hist[j][k] * g2s[63 + k - ph];
        tmp[j][phl] = s;
    }
    __syncthreads();
#pragma unroll
    for (int c = 0; c < 2; c++) {
        int cell = (c << 8) + tid;
        int pv   = cell >> 3;
        int phl  = cell & 7;
        int ph   = (phg << 3) + phl;
        float s = 0.f;
        for (int j = 0; j < 64; j++)
            s += g2s[63 + j - pv] * tmp[j][phl];
        invden[(b * 64 + pv) * 64 + ph] = 1.0f / s;
    }
}

// K1: deterministic bucket lists via wave ballot compaction; posv-axis list
// emitted directly grouped by ph>>4 (two-pass ballot counting-sort). Block 0
// builds the MFMA A-fragment tables; blocks >= nbkt run the kden body.
__global__ __launch_bounds__(256) void k1_bucket(
    const int* __restrict__ posv, const int* __restrict__ posh,
    int* __restrict__ tokv2, int4* __restrict__ goff,
    int* __restrict__ tokh,
    int* __restrict__ cntv, int* __restrict__ cnth,
    float* __restrict__ gbase, ushort_t* __restrict__ AfH,
    ushort_t* __restrict__ AfL, float* __restrict__ invden, int nbkt)
{
    if ((int)blockIdx.x >= nbkt) {            // fused kden blocks
        kden_body((int)blockIdx.x - nbkt, posv, posh, invden, 0);
        return;
    }

    int b    = blockIdx.x >> 5;
    int blk  = blockIdx.x & 31;
    int wave = threadIdx.x >> 6;
    int lane = threadIdx.x & 63;

    if (blockIdx.x == 0) {
        if (threadIdx.x < 192) {
            int k = (int)threadIdx.x - 64;
            float v = 0.0f;
            if (k >= 0 && k < 127) {
                int r = k - 63;
                v = expf(-(float)(r * r) * (1.0f / 512.0f));
            }
            gbase[threadIdx.x] = v;
        }
#pragma unroll
        for (int p = 0; p < 16; p++) {
            int pos = (p << 8) + (int)threadIdx.x;   // 0..4095
            int i   = pos & 7;
            int ln  = (pos >> 3) & 63;
            int ks  = (pos >> 9) & 1;
            int w   = pos >> 10;
            int q   = (w << 4) + (ln & 15);
            int k   = (ks << 5) + ((i >> 2) << 4) + ((ln >> 4) << 2) + (i & 3);
            int dlt = q - k;
            float g = expf(-(float)(dlt * dlt) * (1.0f / 512.0f));
            ushort_t hi = f2bf(g);
            AfH[pos] = hi;
            AfL[pos] = f2bf(g - bf2f(hi));
        }
    }

    int task   = blk * 4 + wave;              // 0..127
    int bucket = task & 63;
    int use_ph = task >> 6;
    int bkt    = b * 64 + bucket;

    // combined per-token meta: posv | posh<<16
    int comb[32];
#pragma unroll
    for (int k = 0; k < 32; k++) {
        int t = k * 64 + lane;
        comb[k] = posv[b * NT + t] | (posh[b * NT + t] << 16);
    }

    unsigned long long lmask = (1ull << lane) - 1ull;

    if (use_ph == 0) {
        // tokv2: tokens with posv==bucket, grouped by ph>>4 (stable order).
        int* dst = tokv2 + (size_t)bkt * CAP;
        int cg0 = 0, cg1 = 0, cg2 = 0, cg3 = 0;
#pragma unroll 4
        for (int k = 0; k < 32; k++) {
            bool hit = (comb[k] & 0xffff) == bucket;
            int grp = (comb[k] >> 20) & 3;
            cg0 += (int)__popcll(__ballot(hit && grp == 0));
            cg1 += (int)__popcll(__ballot(hit && grp == 1));
            cg2 += (int)__popcll(__ballot(hit && grp == 2));
            cg3 += (int)__popcll(__ballot(hit && grp == 3));
        }
        int s1 = cg0, s2 = cg0 + cg1, s3 = cg0 + cg1 + cg2;
        int tot = s3 + cg3;
        if (lane == 0) {
            goff[bkt] = make_int4(0, s1, s2, s3);
            cntv[bkt] = tot;
        }
        int c0 = 0, c1 = s1, c2 = s2, c3 = s3;
#pragma unroll 4
        for (int k = 0; k < 32; k++) {
            bool hit = (comb[k] & 0xffff) == bucket;
            int grp = (comb[k] >> 20) & 3;
            unsigned long long m0 = __ballot(hit && grp == 0);
            unsigned long long m1 = __ballot(hit && grp == 1);
            unsigned long long m2 = __ballot(hit && grp == 2);
            unsigned long long m3 = __ballot(hit && grp == 3);
            if (hit) {
                int p;
                if      (grp == 0) p = c0 + (int)__popcll(m0 & lmask);
                else if (grp == 1) p = c1 + (int)__popcll(m1 & lmask);
                else if (grp == 2) p = c2 + (int)__popcll(m2 & lmask);
                else               p = c3 + (int)__popcll(m3 & lmask);
                dst[p] = (k * 64 + lane) | (comb[k] & 0xffff0000);
            }
            c0 += (int)__popcll(m0); c1 += (int)__popcll(m1);
            c2 += (int)__popcll(m2); c3 += (int)__popcll(m3);
        }
    } else {
        // tokh: tokens with posh==bucket, packed t | posv<<16.
        int* dst = tokh + (size_t)bkt * CAP;
        int cursor = 0;
#pragma unroll 4
        for (int k = 0; k < 32; k++) {
            bool hit = ((comb[k] >> 16) == bucket);
            unsigned long long m = __ballot(hit);
            if (hit)
                dst[cursor + __popcll(m & lmask)] =
                    (k * 64 + lane) | ((comb[k] & 0xffff) << 16);
            cursor += (int)__popcll(m);
        }
        if (lane == 0) cnth[bkt] = cursor;
    }
}

// Standalone kden (loop path only).
__global__ __launch_bounds__(256) void kden(
    const int* __restrict__ posv, const int* __restrict__ posh,
    float* __restrict__ invden, int b0)
{
    kden_body((int)blockIdx.x, posv, posh, invden, b0);
}

// B-fragment load from bf16 LDS rows (k3 path):
// 8 bf16 at k = ks*32 + {4g..4g+3, 16+4g..16+4g+3}, row n.
__device__ __forceinline__ short8 ldsBfrag(const ushort_t* rowp, int ks, int g4) {
    const ushort_t* p = rowp + (ks << 5) + g4;
    uint2 lo = *(const uint2*)(p);
    uint2 hi = *(const uint2*)(p + 16);
    uint4 pk; pk.x = lo.x; pk.y = lo.y; pk.z = hi.x; pk.w = hi.y;
    return __builtin_bit_cast(short8, pk);
}

// B-fragment load from fp32 LDS rows with IN-REGISTER bf16 convert (k2
// round-18): deletes the separate S->S16 convert phase + 2 barriers.
__device__ __forceinline__ short8 ldsBfragF32(const float* rowp, int ks, int g4) {
    const float* p = rowp + (ks << 5) + g4;
    float a0 = p[0],  a1 = p[1],  a2 = p[2],  a3 = p[3];
    float b0 = p[16], b1 = p[17], b2 = p[18], b3 = p[19];
    uint4 pk;
    pk.x = (unsigned int)f2bf(a0) | ((unsigned int)f2bf(a1) << 16);
    pk.y = (unsigned int)f2bf(a2) | ((unsigned int)f2bf(a3) << 16);
    pk.z = (unsigned int)f2bf(b0) | ((unsigned int)f2bf(b1) << 16);
    pk.w = (unsigned int)f2bf(b2) | ((unsigned int)f2bf(b3) << 16);
    return __builtin_bit_cast(short8, pk);
}

// K2: h-conv via MFMA — round-18: MFMA B-fragments read the fp32 S tile
// directly (ldsBfragF32, in-register cvt), deleting the convert phase and
// 2 of 6 barriers. Phase A (LDS-RMW, race-free via k1 grouping) and the
// park+coalesced-store epilogue are unchanged from round 17 (41us).
__global__ __launch_bounds__(256) void k2_convh(
    const float* __restrict__ x,
    const int* __restrict__ tokv2, const int* __restrict__ cntv,
    const int4* __restrict__ goff,
    const ushort_t* __restrict__ AfH, const ushort_t* __restrict__ AfL,
    ushort_t* __restrict__ B1, int b0)
{
    int pv   = blockIdx.x & 63;
    int dc   = (blockIdx.x >> 6) & 15;
    int b    = b0 + (blockIdx.x >> 10);
    int tid  = threadIdx.x;
    int lane = tid & 63;
    int w    = tid >> 6;
    int d0   = dc << 6;

    __shared__ float ldsf[64 * 65];               // 16640 B union buffer
    float    (*S)[65]    = (float(*)[65])ldsf;    // fp32 accum S[d][ph]
    ushort_t (*S16)[68]  = (ushort_t(*)[68])ldsf; // bf16 output park (aliased)

    int bucket = (b << 6) + pv;
    int n = cntv[bucket];
    const int* toks = tokv2 + (size_t)bucket * CAP;
    const float* xb = x + (((size_t)b * NT) << 10) + d0 + lane;

    int4 go = goff[bucket];
    int gs = (w == 0) ? go.x : (w == 1) ? go.y : (w == 2) ? go.z : go.w;
    int ge = (w == 3) ? n   : (w == 0) ? go.y : (w == 1) ? go.z : go.w;

    // --- prefetch window 0 (meta + first 8 gathers) before LDS zeroing ---
    int wn0 = ge - gs; if (wn0 < 0) wn0 = 0; if (wn0 > 64) wn0 = 64;
    int m0  = wn0 > 8 ? 8 : wn0;
    int pkv = (wn0 > 0) ? toks[gs + lane] : 0;
    int pk0[8]; float xv0[8];
#pragma unroll
    for (int j = 0; j < 8; j++) pk0[j] = __builtin_amdgcn_readlane(pkv, j);
#pragma unroll
    for (int j = 0; j < 8; j++)
        if (j < m0) xv0[j] = xb[(size_t)(pk0[j] & 0xffff) << 10];

    // A-fragments issued early too (L2-resident after first blocks).
    short8 ahi[2], alo[2];
#pragma unroll
    for (int ks = 0; ks < 2; ks++) {
        int idx = ((((w << 1) + ks) << 6) + lane) << 3;
        ahi[ks] = *(const short8*)(AfH + idx);
        alo[ks] = *(const short8*)(AfL + idx);
    }

    // zero S while the loads are in flight
#pragma unroll
    for (int k = 0; k < 17; k++) {
        int idx = (k << 8) + tid;
        if (idx < 64 * 65) ldsf[idx] = 0.f;
    }
    __syncthreads();                              // barrier 1

    // consume prefetched batch
#pragma unroll
    for (int j = 0; j < 8; j++)
        if (j < m0) S[lane][pk0[j] >> 16] += xv0[j];

    // rest of window 0
    for (int i = 8; i < wn0; i += 8) {
        int m = wn0 - i; if (m > 8) m = 8;
        int pk[8]; float xv[8];
#pragma unroll
        for (int j = 0; j < 8; j++) pk[j] = __builtin_amdgcn_readlane(pkv, i + j);
#pragma unroll
        for (int j = 0; j < 8; j++)
            if (j < m) xv[j] = xb[(size_t)(pk[j] & 0xffff) << 10];
#pragma unroll
        for (int j = 0; j < 8; j++)
            if (j < m) S[lane][pk[j] >> 16] += xv[j];
    }
    // windows 1.. (rare: wave-group >64 tokens)
    for (int win = gs + 64; win < ge; win += 64) {
        int wn = ge - win; if (wn > 64) wn = 64;
        int pkw = toks[win + lane];
        for (int i = 0; i < wn; i += 8) {
            int m = wn - i; if (m > 8) m = 8;
            int pk[8]; float xv[8];
#pragma unroll
            for (int j = 0; j < 8; j++) pk[j] = __builtin_amdgcn_readlane(pkw, i + j);
#pragma unroll
            for (int j = 0; j < 8; j++)
                if (j < m) xv[j] = xb[(size_t)(pk[j] & 0xffff) << 10];
#pragma unroll
            for (int j = 0; j < 8; j++)
                if (j < m) S[lane][pk[j] >> 16] += xv[j];
        }
    }
    __syncthreads();                              // barrier 2: S complete

    // MFMA: Y[q][d] = (Ghi + Glo) . S (fragments read fp32, cvt in-reg)
    int g4 = (lane >> 4) << 2;
    int qbase = (w << 4) + g4;

    f32x4 accs[4];
#pragma unroll
    for (int nt = 0; nt < 4; nt++) {
        const float* rowp = &S[(nt << 4) + (lane & 15)][0];
        f32x4 a = {0.f, 0.f, 0.f, 0.f};
#pragma unroll
        for (int ks = 0; ks < 2; ks++) {
            short8 bf = ldsBfragF32(rowp, ks, g4);
            a = __builtin_amdgcn_mfma_f32_16x16x32_bf16(ahi[ks], bf, a, 0, 0, 0);
            a = __builtin_amdgcn_mfma_f32_16x16x32_bf16(alo[ks], bf, a, 0, 0, 0);
        }
        accs[nt] = a;
    }
    __syncthreads();                              // barrier 3: S reads done

    // Park results (rows=q, cols=d_local) in aliased bf16 layout.
#pragma unroll
    for (int nt = 0; nt < 4; nt++)
#pragma unroll
        for (int reg = 0; reg < 4; reg++)
            S16[qbase + reg][(nt << 4) + (lane & 15)] = f2bf(accs[nt][reg]);
    __syncthreads();                              // barrier 4

    ushort_t* B1p = B1 + (((size_t)(b - b0)) << 22) + (((size_t)pv) << 10) + d0;
#pragma unroll
    for (int pass = 0; pass < 2; pass++) {
        int row = (pass << 5) + (tid >> 3);      // 32 rows per pass
        int col = (tid & 7) << 3;                // 8 ushorts per thread
        uint4 v = *(const uint4*)(&S16[row][col]);
        *reinterpret_cast<uint4*>(B1p + ((size_t)row << 16) + col) = v;
    }
}

// K3: v-conv via MFMA + token scatter (unchanged — near traffic floor).
__global__ __launch_bounds__(256) void k3_convv(
    const int* __restrict__ tokh, const int* __restrict__ cnth,
    const ushort_t* __restrict__ AfH, const ushort_t* __restrict__ AfL,
    const ushort_t* __restrict__ B1, const float* __restrict__ invden,
    float* __restrict__ out, int b0)
{
    int ph   = blockIdx.x & 63;
    int dc   = (blockIdx.x >> 6) & 15;
    int b    = b0 + (blockIdx.x >> 10);
    int tid  = threadIdx.x;
    int lane = tid & 63;
    int w    = tid >> 6;
    int d0   = dc << 6;

    int n = cnth[(b << 6) + ph];
    if (n == 0) return;               // uniform across block

    __shared__ float ldsf[64 * 65];              // 16640 B union buffer
    ushort_t (*u16)[68] = (ushort_t(*)[68])ldsf; // staged B1 column
    float    (*y)[65]   = (float(*)[65])ldsf;    // conv output

    const ushort_t* B1b = B1 + (((size_t)(b - b0)) << 22) + (((size_t)ph) << 16)
                        + d0 + lane;
#pragma unroll
    for (int it = 0; it < 16; it++) {
        int j = (w << 4) + it;
        u16[lane][j] = B1b[(size_t)j << 10];
    }
    __syncthreads();

    short8 ahi[2], alo[2];
#pragma unroll
    for (int ks = 0; ks < 2; ks++) {
        int idx = ((((w << 1) + ks) << 6) + lane) << 3;
        ahi[ks] = *(const short8*)(AfH + idx);
        alo[ks] = *(const short8*)(AfL + idx);
    }
    int g4 = (lane >> 4) << 2;
    int qbase = (w << 4) + g4;

    f32x4 accs[4];
#pragma unroll
    for (int nt = 0; nt < 4; nt++) {
        const ushort_t* rowp = &u16[(nt << 4) + (lane & 15)][0];
        f32x4 a = {0.f, 0.f, 0.f, 0.f};
#pragma unroll
        for (int ks = 0; ks < 2; ks++) {
            short8 bf = ldsBfrag(rowp, ks, g4);
            a = __builtin_amdgcn_mfma_f32_16x16x32_bf16(ahi[ks], bf, a, 0, 0, 0);
            a = __builtin_amdgcn_mfma_f32_16x16x32_bf16(alo[ks], bf, a, 0, 0, 0);
        }
        accs[nt] = a;
    }
    __syncthreads();                   // all u16 reads done before y writes

#pragma unroll
    for (int nt = 0; nt < 4; nt++)
#pragma unroll
        for (int reg = 0; reg < 4; reg++)
            y[qbase + reg][(nt << 4) + (lane & 15)] = accs[nt][reg];
    __syncthreads();

    const int* toks = tokh + ((size_t)((b << 6) + ph)) * CAP;
    float* outb = out + (((size_t)b * NT) << 10) + d0 + lane;
    const float* ivb = invden + ((b << 6) << 6) + ph;

    int nch = (n + 3) >> 2;
    for (int c = w; c < nch; c += 4) {
        int i0 = c << 2;
        int4 M = *(const int4*)(toks + i0);   // safe past n: ws mapped
        int pk[4];
        pk[0] = __builtin_amdgcn_readfirstlane(M.x);
        pk[1] = __builtin_amdgcn_readfirstlane(M.y);
        pk[2] = __builtin_amdgcn_readfirstlane(M.z);
        pk[3] = __builtin_amdgcn_readfirstlane(M.w);
#pragma unroll
        for (int j = 0; j < 4; j++) {
            if (i0 + j < n) {
                int t   = pk[j] & 0xffff;
                int pvt = pk[j] >> 16;
                float iv = ivb[pvt << 6];
                outb[(size_t)t << 10] = y[pvt][lane] * iv;
            }
        }
    }
}

// Safety-net fallback (no workspace needed): direct O(T^2 * D) attention.
__global__ __launch_bounds__(256) void k_naive(
    const float* __restrict__ x, const int* __restrict__ posv,
    const int* __restrict__ posh, float* __restrict__ out)
{
    int t   = blockIdx.x & (NT - 1);
    int b   = blockIdx.x >> 11;
    int tid = threadIdx.x;

    __shared__ float s_w[NT];
    __shared__ float s_red[256];

    int pvt = posv[b * NT + t];
    int pht = posh[b * NT + t];

    float dsum = 0.0f;
    for (int s = tid; s < NT; s += 256) {
        int dv = pvt - posv[b * NT + s];
        int dh = pht - posh[b * NT + s];
        float w = expf(-(float)(dv * dv + dh * dh) * (1.0f / 512.0f));
        s_w[s] = w;
        dsum += w;
    }
    s_red[tid] = dsum;
    __syncthreads();
    for (int off = 128; off > 0; off >>= 1) {
        if (tid < off) s_red[tid] += s_red[tid + off];
        __syncthreads();
    }
    float inv = 1.0f / s_red[0];

    float a0 = 0.f, a1 = 0.f, a2 = 0.f, a3 = 0.f;
    for (int s = 0; s < NT; s++) {
        float w = s_w[s];
        const float* xr = x + (((size_t)(b * NT + s)) << 10);
        a0 = fmaf(w, xr[tid + 0],   a0);
        a1 = fmaf(w, xr[tid + 256], a1);
        a2 = fmaf(w, xr[tid + 512], a2);
        a3 = fmaf(w, xr[tid + 768], a3);
    }
    size_t ob = (((size_t)(b * NT + t)) << 10) + tid;
    out[ob + 0]   = a0 * inv;
    out[ob + 256] = a1 * inv;
    out[ob + 512] = a2 * inv;
    out[ob + 768] = a3 * inv;
}

extern "C" void kernel_launch(void* const* d_in, const int* in_sizes, int n_in,
                              void* d_out, int out_size, void* d_ws, size_t ws_size,
                              hipStream_t stream) {
    const float* x    = (const float*)d_in[0];
    const int*   posv = (const int*)d_in[1];
    const int*   posh = (const int*)d_in[2];
    float*       out  = (float*)d_out;

    char* ws = (char*)d_ws;
    float*    gbase  = (float*)ws;
    ushort_t* AfH    = (ushort_t*)(ws + OFF_AFH);
    ushort_t* AfL    = (ushort_t*)(ws + OFF_AFL);
    int*      cntv   = (int*)(ws + OFF_CNTV);
    int*      cnth   = (int*)(ws + OFF_CNTH);
    float*    invden = (float*)(ws + OFF_INVDEN);
    int4*     goff   = (int4*)(ws + OFF_GOFF);
    int*      tokh   = (int*)(ws + OFF_TOKH);
    int*      tokv2  = (int*)(ws + OFF_TOKV2);
    ushort_t* B1     = (ushort_t*)(ws + OFF_B1);

    const size_t needFull = (size_t)OFF_B1 + (size_t)NB * B1_SLAB;   // ~80 MB
    const size_t needLoop = (size_t)OFF_B1 + B1_SLAB;                // ~21 MB

    if (ws_size >= needFull) {
        // k1 (256 bucket blocks, emits grouped tokv2 directly) + fused kden
        k1_bucket<<<NB * 32 + NB * 8, 256, 0, stream>>>(
            posv, posh, tokv2, goff, tokh, cntv, cnth, gbase, AfH, AfL,
            invden, NB * 32);
        k2_convh<<<NB * 1024, 256, 0, stream>>>(x, tokv2, cntv, goff, AfH, AfL, B1, 0);
        k3_convv<<<NB * 1024, 256, 0, stream>>>(tokh, cnth, AfH, AfL, B1, invden, out, 0);
    } else if (ws_size >= needLoop) {
        k1_bucket<<<NB * 32, 256, 0, stream>>>(
            posv, posh, tokv2, goff, tokh, cntv, cnth, gbase, AfH, AfL,
            invden, NB * 32);
        for (int b = 0; b < NB; b++) {
            kden<<<8, 256, 0, stream>>>(posv, posh, invden, b);
            k2_convh<<<1024, 256, 0, stream>>>(x, tokv2, cntv, goff, AfH, AfL, B1, b);
            k3_convv<<<1024, 256, 0, stream>>>(tokh, cnth, AfH, AfL, B1, invden, out, b);
        }
    } else {
        k_naive<<<NB * NT, 256, 0, stream>>>(x, posv, posh, out);
    }
}

// Round 19
// 73.115 us; speedup vs baseline: 1.0617x; 1.0617x over previous
//
#include <hip/hip_runtime.h>
#include <hip/hip_bf16.h>

// Problem constants (fixed by setup_inputs): B=8, T=2048, D=1024, positions in [0,64).
#define NB 8
#define NT 2048
#define ND 1024
#define CAP 2048

typedef unsigned short ushort_t;
using short8 = __attribute__((ext_vector_type(8))) short;   // 8 bf16 (4 VGPR)
using f32x4  = __attribute__((ext_vector_type(4))) float;   // MFMA accum

__device__ __forceinline__ ushort_t f2bf(float f) {
    __hip_bfloat16 h = __float2bfloat16(f);
    return *reinterpret_cast<ushort_t*>(&h);
}
__device__ __forceinline__ float bf2f(ushort_t u) {
    unsigned int v = ((unsigned int)u) << 16;
    return __int_as_float((int)v);
}

// XCD-aware bijective block swizzle (T1): HW assigns block i to XCD i%8;
// ell = (bid>>3) + (bid&7)*(nwg/8) gives each XCD a CONTIGUOUS logical
// range, so concurrent blocks on one XCD share x/B1 panels -> L2-resident
// gathers (k2 is gather-latency-bound: all pipes <25%). Requires nwg%8==0
// (8192 and 1024 both qualify). Round-18's fp32-fragment experiment is
// reverted (4.19M LDS bank conflicts at stride-65: +4us).
__device__ __forceinline__ int xcd_swizzle() {
    int bid = (int)blockIdx.x;
    return (bid >> 3) + ((bid & 7) * ((int)gridDim.x >> 3));
}

// MFMA operand K-slot mapping for 16x16x32 bf16: k(g,i) = (i>>2)*16+4g+(i&3),
// g = lane>>4. Consistent on A-table (k1) and B-reads (k2/k3) -> any
// permutation error cancels over the reduction axis. C/D: col=lane&15,
// row=4*(lane>>4)+reg [HW-verified]. (Validated: rounds 13-18 absmax.)

// ---------------------------------------------------------------------------
// Workspace layout (byte offsets):
// ---------------------------------------------------------------------------
#define OFF_G2     256
#define OFF_AFH    768
#define OFF_AFL    8960
#define OFF_CNTV   17152
#define OFF_CNTH   19200
#define OFF_INVDEN 21248
#define OFF_GOFF   152320
#define OFF_TOKV   160512
#define OFF_TOKH   4354816
#define OFF_TOKV2  8549120
#define OFF_B1     12743424
#define B1_SLAB    ((size_t)64 * 64 * 1024 * 2)   // 8 MB per batch (bf16)

// Shared kden body: denominator table via LDS-atomic INTEGER histogram
// (deterministic) + two 64x64 mini-matmuls. g table computed locally.
__device__ __forceinline__ void kden_body(
    int kb, const int* __restrict__ posv, const int* __restrict__ posh,
    float* __restrict__ invden, int b0)
{
    int b   = b0 + (kb >> 3);
    int phg = kb & 7;
    int tid = threadIdx.x;

    __shared__ int   hist[64][64];
    __shared__ float g2s[128];
    __shared__ float tmp[64][8];

#pragma unroll
    for (int k = 0; k < 16; k++) ((int*)hist)[tid + (k << 8)] = 0;
    if (tid < 128) {
        int k = tid, r = k - 63;
        g2s[tid] = (k < 127) ? expf(-(float)(r * r) * (1.0f / 512.0f)) : 0.0f;
    }
    __syncthreads();
#pragma unroll
    for (int k = 0; k < 8; k++) {
        int t = (k << 8) + tid;
        atomicAdd(&hist[posv[b * NT + t]][posh[b * NT + t]], 1);
    }
    __syncthreads();
#pragma unroll
    for (int c = 0; c < 2; c++) {
        int cell = (c << 8) + tid;
        int j    = cell >> 3;
        int phl  = cell & 7;
        int ph   = (phg << 3) + phl;
        float s = 0.f;
        for (int k = 0; k < 64; k++)
            s += (float)hist[j][k] * g2s[63 + k - ph];
        tmp[j][phl] = s;
    }
    __syncthreads();
#pragma unroll
    for (int c = 0; c < 2; c++) {
        int cell = (c << 8) + tid;
        int pv   = cell >> 3;
        int phl  = cell & 7;
        int ph   = (phg << 3) + phl;
        float s = 0.f;
        for (int j = 0; j < 64; j++)
            s += g2s[63 + j - pv] * tmp[j][phl];
        invden[(b * 64 + pv) * 64 + ph] = 1.0f / s;
    }
}

// K1: deterministic bucket lists via wave ballot compaction; posv-axis list
// emitted directly grouped by ph>>4 (two-pass ballot counting-sort). Block 0
// builds the MFMA A-fragment tables; blocks >= nbkt run the kden body.
__global__ __launch_bounds__(256) void k1_bucket(
    const int* __restrict__ posv, const int* __restrict__ posh,
    int* __restrict__ tokv2, int4* __restrict__ goff,
    int* __restrict__ tokh,
    int* __restrict__ cntv, int* __restrict__ cnth,
    float* __restrict__ gbase, ushort_t* __restrict__ AfH,
    ushort_t* __restrict__ AfL, float* __restrict__ invden, int nbkt)
{
    if ((int)blockIdx.x >= nbkt) {            // fused kden blocks
        kden_body((int)blockIdx.x - nbkt, posv, posh, invden, 0);
        return;
    }

    int b    = blockIdx.x >> 5;
    int blk  = blockIdx.x & 31;
    int wave = threadIdx.x >> 6;
    int lane = threadIdx.x & 63;

    if (blockIdx.x == 0) {
        if (threadIdx.x < 192) {
            int k = (int)threadIdx.x - 64;
            float v = 0.0f;
            if (k >= 0 && k < 127) {
                int r = k - 63;
                v = expf(-(float)(r * r) * (1.0f / 512.0f));
            }
            gbase[threadIdx.x] = v;
        }
#pragma unroll
        for (int p = 0; p < 16; p++) {
            int pos = (p << 8) + (int)threadIdx.x;   // 0..4095
            int i   = pos & 7;
            int ln  = (pos >> 3) & 63;
            int ks  = (pos >> 9) & 1;
            int w   = pos >> 10;
            int q   = (w << 4) + (ln & 15);
            int k   = (ks << 5) + ((i >> 2) << 4) + ((ln >> 4) << 2) + (i & 3);
            int dlt = q - k;
            float g = expf(-(float)(dlt * dlt) * (1.0f / 512.0f));
            ushort_t hi = f2bf(g);
            AfH[pos] = hi;
            AfL[pos] = f2bf(g - bf2f(hi));
        }
    }

    int task   = blk * 4 + wave;              // 0..127
    int bucket = task & 63;
    int use_ph = task >> 6;
    int bkt    = b * 64 + bucket;

    // combined per-token meta: posv | posh<<16
    int comb[32];
#pragma unroll
    for (int k = 0; k < 32; k++) {
        int t = k * 64 + lane;
        comb[k] = posv[b * NT + t] | (posh[b * NT + t] << 16);
    }

    unsigned long long lmask = (1ull << lane) - 1ull;

    if (use_ph == 0) {
        // tokv2: tokens with posv==bucket, grouped by ph>>4 (stable order).
        int* dst = tokv2 + (size_t)bkt * CAP;
        int cg0 = 0, cg1 = 0, cg2 = 0, cg3 = 0;
#pragma unroll 4
        for (int k = 0; k < 32; k++) {
            bool hit = (comb[k] & 0xffff) == bucket;
            int grp = (comb[k] >> 20) & 3;
            cg0 += (int)__popcll(__ballot(hit && grp == 0));
            cg1 += (int)__popcll(__ballot(hit && grp == 1));
            cg2 += (int)__popcll(__ballot(hit && grp == 2));
            cg3 += (int)__popcll(__ballot(hit && grp == 3));
        }
        int s1 = cg0, s2 = cg0 + cg1, s3 = cg0 + cg1 + cg2;
        int tot = s3 + cg3;
        if (lane == 0) {
            goff[bkt] = make_int4(0, s1, s2, s3);
            cntv[bkt] = tot;
        }
        int c0 = 0, c1 = s1, c2 = s2, c3 = s3;
#pragma unroll 4
        for (int k = 0; k < 32; k++) {
            bool hit = (comb[k] & 0xffff) == bucket;
            int grp = (comb[k] >> 20) & 3;
            unsigned long long m0 = __ballot(hit && grp == 0);
            unsigned long long m1 = __ballot(hit && grp == 1);
            unsigned long long m2 = __ballot(hit && grp == 2);
            unsigned long long m3 = __ballot(hit && grp == 3);
            if (hit) {
                int p;
                if      (grp == 0) p = c0 + (int)__popcll(m0 & lmask);
                else if (grp == 1) p = c1 + (int)__popcll(m1 & lmask);
                else if (grp == 2) p = c2 + (int)__popcll(m2 & lmask);
                else               p = c3 + (int)__popcll(m3 & lmask);
                dst[p] = (k * 64 + lane) | (comb[k] & 0xffff0000);
            }
            c0 += (int)__popcll(m0); c1 += (int)__popcll(m1);
            c2 += (int)__popcll(m2); c3 += (int)__popcll(m3);
        }
    } else {
        // tokh: tokens with posh==bucket, packed t | posv<<16.
        int* dst = tokh + (size_t)bkt * CAP;
        int cursor = 0;
#pragma unroll 4
        for (int k = 0; k < 32; k++) {
            bool hit = ((comb[k] >> 16) == bucket);
            unsigned long long m = __ballot(hit);
            if (hit)
                dst[cursor + __popcll(m & lmask)] =
                    (k * 64 + lane) | ((comb[k] & 0xffff) << 16);
            cursor += (int)__popcll(m);
        }
        if (lane == 0) cnth[bkt] = cursor;
    }
}

// Standalone kden (loop path only).
__global__ __launch_bounds__(256) void kden(
    const int* __restrict__ posv, const int* __restrict__ posh,
    float* __restrict__ invden, int b0)
{
    kden_body((int)blockIdx.x, posv, posh, invden, b0);
}

// B-fragment load: 8 bf16 at k = ks*32 + {4g..4g+3, 16+4g..16+4g+3}, row n.
__device__ __forceinline__ short8 ldsBfrag(const ushort_t* rowp, int ks, int g4) {
    const ushort_t* p = rowp + (ks << 5) + g4;
    uint2 lo = *(const uint2*)(p);
    uint2 hi = *(const uint2*)(p + 16);
    uint4 pk; pk.x = lo.x; pk.y = lo.y; pk.z = hi.x; pk.w = hi.y;
    return __builtin_bit_cast(short8, pk);
}

// K2: h-conv via MFMA — round-17 structure (proven 41us, 0 bank conflicts)
// + XCD swizzle. LDS: one 16.6KB union buffer (S fp32 / S16 bf16,
// barrier-disciplined in-place convert). Phase A RMW race-free via k1
// grouping; window-0 prefetch before LDS zeroing.
__global__ __launch_bounds__(256) void k2_convh(
    const float* __restrict__ x,
    const int* __restrict__ tokv2, const int* __restrict__ cntv,
    const int4* __restrict__ goff,
    const ushort_t* __restrict__ AfH, const ushort_t* __restrict__ AfL,
    ushort_t* __restrict__ B1, int b0)
{
    int ell  = xcd_swizzle();
    int pv   = ell & 63;
    int dc   = (ell >> 6) & 15;
    int b    = b0 + (ell >> 10);
    int tid  = threadIdx.x;
    int lane = tid & 63;
    int w    = tid >> 6;
    int d0   = dc << 6;

    __shared__ float ldsf[64 * 65];               // 16640 B union buffer
    float    (*S)[65]   = (float(*)[65])ldsf;     // fp32 accum  S[d][ph]
    ushort_t (*S16)[68] = (ushort_t(*)[68])ldsf;  // bf16 operand / output

    int bucket = (b << 6) + pv;
    int n = cntv[bucket];
    const int* toks = tokv2 + (size_t)bucket * CAP;
    const float* xb = x + (((size_t)b * NT) << 10) + d0 + lane;

    int4 go = goff[bucket];
    int gs = (w == 0) ? go.x : (w == 1) ? go.y : (w == 2) ? go.z : go.w;
    int ge = (w == 3) ? n   : (w == 0) ? go.y : (w == 1) ? go.z : go.w;

    // --- prefetch window 0 (meta + first 8 gathers) before LDS zeroing ---
    int wn0 = ge - gs; if (wn0 < 0) wn0 = 0; if (wn0 > 64) wn0 = 64;
    int m0  = wn0 > 8 ? 8 : wn0;
    int pkv = (wn0 > 0) ? toks[gs + lane] : 0;
    int pk0[8]; float xv0[8];
#pragma unroll
    for (int j = 0; j < 8; j++) pk0[j] = __builtin_amdgcn_readlane(pkv, j);
#pragma unroll
    for (int j = 0; j < 8; j++)
        if (j < m0) xv0[j] = xb[(size_t)(pk0[j] & 0xffff) << 10];

    // zero S while the loads are in flight
#pragma unroll
    for (int k = 0; k < 17; k++) {
        int idx = (k << 8) + tid;
        if (idx < 64 * 65) ldsf[idx] = 0.f;
    }
    __syncthreads();

    // consume prefetched batch
#pragma unroll
    for (int j = 0; j < 8; j++)
        if (j < m0) S[lane][pk0[j] >> 16] += xv0[j];

    // rest of window 0
    for (int i = 8; i < wn0; i += 8) {
        int m = wn0 - i; if (m > 8) m = 8;
        int pk[8]; float xv[8];
#pragma unroll
        for (int j = 0; j < 8; j++) pk[j] = __builtin_amdgcn_readlane(pkv, i + j);
#pragma unroll
        for (int j = 0; j < 8; j++)
            if (j < m) xv[j] = xb[(size_t)(pk[j] & 0xffff) << 10];
#pragma unroll
        for (int j = 0; j < 8; j++)
            if (j < m) S[lane][pk[j] >> 16] += xv[j];
    }
    // windows 1.. (rare: wave-group >64 tokens)
    for (int win = gs + 64; win < ge; win += 64) {
        int wn = ge - win; if (wn > 64) wn = 64;
        int pkw = toks[win + lane];
        for (int i = 0; i < wn; i += 8) {
            int m = wn - i; if (m > 8) m = 8;
            int pk[8]; float xv[8];
#pragma unroll
            for (int j = 0; j < 8; j++) pk[j] = __builtin_amdgcn_readlane(pkw, i + j);
#pragma unroll
            for (int j = 0; j < 8; j++)
                if (j < m) xv[j] = xb[(size_t)(pk[j] & 0xffff) << 10];
#pragma unroll
            for (int j = 0; j < 8; j++)
                if (j < m) S[lane][pk[j] >> 16] += xv[j];
        }
    }
    __syncthreads();

    // in-place fp32 -> bf16 convert (read to regs, barrier, aliased write)
    {
        int r  = tid & 63;
        int c0 = (tid >> 6) << 4;
        float vals[16];
#pragma unroll
        for (int c = 0; c < 16; c++) vals[c] = S[r][c0 + c];
        __syncthreads();
#pragma unroll
        for (int c = 0; c < 16; c++) S16[r][c0 + c] = f2bf(vals[c]);
    }
    __syncthreads();

    // MFMA: Y[q][d] = (Ghi + Glo) . S16
    short8 ahi[2], alo[2];
#pragma unroll
    for (int ks = 0; ks < 2; ks++) {
        int idx = ((((w << 1) + ks) << 6) + lane) << 3;
        ahi[ks] = *(const short8*)(AfH + idx);
        alo[ks] = *(const short8*)(AfL + idx);
    }
    int g4 = (lane >> 4) << 2;
    int qbase = (w << 4) + g4;

    f32x4 accs[4];
#pragma unroll
    for (int nt = 0; nt < 4; nt++) {
        const ushort_t* rowp = &S16[(nt << 4) + (lane & 15)][0];
        f32x4 a = {0.f, 0.f, 0.f, 0.f};
#pragma unroll
        for (int ks = 0; ks < 2; ks++) {
            short8 bf = ldsBfrag(rowp, ks, g4);
            a = __builtin_amdgcn_mfma_f32_16x16x32_bf16(ahi[ks], bf, a, 0, 0, 0);
            a = __builtin_amdgcn_mfma_f32_16x16x32_bf16(alo[ks], bf, a, 0, 0, 0);
        }
        accs[nt] = a;
    }
    __syncthreads();                   // all S16 B-fragment reads done

    // Park results (rows=q, cols=d_local), then coalesced store.
#pragma unroll
    for (int nt = 0; nt < 4; nt++)
#pragma unroll
        for (int reg = 0; reg < 4; reg++)
            S16[qbase + reg][(nt << 4) + (lane & 15)] = f2bf(accs[nt][reg]);
    __syncthreads();

    ushort_t* B1p = B1 + (((size_t)(b - b0)) << 22) + (((size_t)pv) << 10) + d0;
#pragma unroll
    for (int pass = 0; pass < 2; pass++) {
        int row = (pass << 5) + (tid >> 3);      // 32 rows per pass
        int col = (tid & 7) << 3;                // 8 ushorts per thread
        uint4 v = *(const uint4*)(&S16[row][col]);
        *reinterpret_cast<uint4*>(B1p + ((size_t)row << 16) + col) = v;
    }
}

// K3: v-conv via MFMA + token scatter (round-17 structure + XCD swizzle).
__global__ __launch_bounds__(256) void k3_convv(
    const int* __restrict__ tokh, const int* __restrict__ cnth,
    const ushort_t* __restrict__ AfH, const ushort_t* __restrict__ AfL,
    const ushort_t* __restrict__ B1, const float* __restrict__ invden,
    float* __restrict__ out, int b0)
{
    int ell  = xcd_swizzle();
    int ph   = ell & 63;
    int dc   = (ell >> 6) & 15;
    int b    = b0 + (ell >> 10);
    int tid  = threadIdx.x;
    int lane = tid & 63;
    int w    = tid >> 6;
    int d0   = dc << 6;

    int n = cnth[(b << 6) + ph];
    if (n == 0) return;               // uniform across block

    __shared__ float ldsf[64 * 65];              // 16640 B union buffer
    ushort_t (*u16)[68] = (ushort_t(*)[68])ldsf; // staged B1 column
    float    (*y)[65]   = (float(*)[65])ldsf;    // conv output

    const ushort_t* B1b = B1 + (((size_t)(b - b0)) << 22) + (((size_t)ph) << 16)
                        + d0 + lane;
#pragma unroll
    for (int it = 0; it < 16; it++) {
        int j = (w << 4) + it;
        u16[lane][j] = B1b[(size_t)j << 10];
    }
    __syncthreads();

    short8 ahi[2], alo[2];
#pragma unroll
    for (int ks = 0; ks < 2; ks++) {
        int idx = ((((w << 1) + ks) << 6) + lane) << 3;
        ahi[ks] = *(const short8*)(AfH + idx);
        alo[ks] = *(const short8*)(AfL + idx);
    }
    int g4 = (lane >> 4) << 2;
    int qbase = (w << 4) + g4;

    f32x4 accs[4];
#pragma unroll
    for (int nt = 0; nt < 4; nt++) {
        const ushort_t* rowp = &u16[(nt << 4) + (lane & 15)][0];
        f32x4 a = {0.f, 0.f, 0.f, 0.f};
#pragma unroll
        for (int ks = 0; ks < 2; ks++) {
            short8 bf = ldsBfrag(rowp, ks, g4);
            a = __builtin_amdgcn_mfma_f32_16x16x32_bf16(ahi[ks], bf, a, 0, 0, 0);
            a = __builtin_amdgcn_mfma_f32_16x16x32_bf16(alo[ks], bf, a, 0, 0, 0);
        }
        accs[nt] = a;
    }
    __syncthreads();                   // all u16 reads done before y writes

#pragma unroll
    for (int nt = 0; nt < 4; nt++)
#pragma unroll
        for (int reg = 0; reg < 4; reg++)
            y[qbase + reg][(nt << 4) + (lane & 15)] = accs[nt][reg];
    __syncthreads();

    const int* toks = tokh + ((size_t)((b << 6) + ph)) * CAP;
    float* outb = out + (((size_t)b * NT) << 10) + d0 + lane;
    const float* ivb = invden + ((b << 6) << 6) + ph;

    int nch = (n + 3) >> 2;
    for (int c = w; c < nch; c += 4) {
        int i0 = c << 2;
        int4 M = *(const int4*)(toks + i0);   // safe past n: ws mapped
        int pk[4];
        pk[0] = __builtin_amdgcn_readfirstlane(M.x);
        pk[1] = __builtin_amdgcn_readfirstlane(M.y);
        pk[2] = __builtin_amdgcn_readfirstlane(M.z);
        pk[3] = __builtin_amdgcn_readfirstlane(M.w);
#pragma unroll
        for (int j = 0; j < 4; j++) {
            if (i0 + j < n) {
                int t   = pk[j] & 0xffff;
                int pvt = pk[j] >> 16;
                float iv = ivb[pvt << 6];
                outb[(size_t)t << 10] = y[pvt][lane] * iv;
            }
        }
    }
}

// Safety-net fallback (no workspace needed): direct O(T^2 * D) attention.
__global__ __launch_bounds__(256) void k_naive(
    const float* __restrict__ x, const int* __restrict__ posv,
    const int* __restrict__ posh, float* __restrict__ out)
{
    int t   = blockIdx.x & (NT - 1);
    int b   = blockIdx.x >> 11;
    int tid = threadIdx.x;

    __shared__ float s_w[NT];
    __shared__ float s_red[256];

    int pvt = posv[b * NT + t];
    int pht = posh[b * NT + t];

    float dsum = 0.0f;
    for (int s = tid; s < NT; s += 256) {
        int dv = pvt - posv[b * NT + s];
        int dh = pht - posh[b * NT + s];
        float w = expf(-(float)(dv * dv + dh * dh) * (1.0f / 512.0f));
        s_w[s] = w;
        dsum += w;
    }
    s_red[tid] = dsum;
    __syncthreads();
    for (int off = 128; off > 0; off >>= 1) {
        if (tid < off) s_red[tid] += s_red[tid + off];
        __syncthreads();
    }
    float inv = 1.0f / s_red[0];

    float a0 = 0.f, a1 = 0.f, a2 = 0.f, a3 = 0.f;
    for (int s = 0; s < NT; s++) {
        float w = s_w[s];
        const float* xr = x + (((size_t)(b * NT + s)) << 10);
        a0 = fmaf(w, xr[tid + 0],   a0);
        a1 = fmaf(w, xr[tid + 256], a1);
        a2 = fmaf(w, xr[tid + 512], a2);
        a3 = fmaf(w, xr[tid + 768], a3);
    }
    size_t ob = (((size_t)(b * NT + t)) << 10) + tid;
    out[ob + 0]   = a0 * inv;
    out[ob + 256] = a1 * inv;
    out[ob + 512] = a2 * inv;
    out[ob + 768] = a3 * inv;
}

extern "C" void kernel_launch(void* const* d_in, const int* in_sizes, int n_in,
                              void* d_out, int out_size, void* d_ws, size_t ws_size,
                              hipStream_t stream) {
    const float* x    = (const float*)d_in[0];
    const int*   posv = (const int*)d_in[1];
    const int*   posh = (const int*)d_in[2];
    float*       out  = (float*)d_out;

    char* ws = (char*)d_ws;
    float*    gbase  = (float*)ws;
    ushort_t* AfH    = (ushort_t*)(ws + OFF_AFH);
    ushort_t* AfL    = (ushort_t*)(ws + OFF_AFL);
    int*      cntv   = (int*)(ws + OFF_CNTV);
    int*      cnth   = (int*)(ws + OFF_CNTH);
    float*    invden = (float*)(ws + OFF_INVDEN);
    int4*     goff   = (int4*)(ws + OFF_GOFF);
    int*      tokh   = (int*)(ws + OFF_TOKH);
    int*      tokv2  = (int*)(ws + OFF_TOKV2);
    ushort_t* B1     = (ushort_t*)(ws + OFF_B1);

    const size_t needFull = (size_t)OFF_B1 + (size_t)NB * B1_SLAB;   // ~80 MB
    const size_t needLoop = (size_t)OFF_B1 + B1_SLAB;                // ~21 MB

    if (ws_size >= needFull) {
        // k1 (256 bucket blocks, emits grouped tokv2 directly) + fused kden
        k1_bucket<<<NB * 32 + NB * 8, 256, 0, stream>>>(
            posv, posh, tokv2, goff, tokh, cntv, cnth, gbase, AfH, AfL,
            invden, NB * 32);
        k2_convh<<<NB * 1024, 256, 0, stream>>>(x, tokv2, cntv, goff, AfH, AfL, B1, 0);
        k3_convv<<<NB * 1024, 256, 0, stream>>>(tokh, cnth, AfH, AfL, B1, invden, out, 0);
    } else if (ws_size >= needLoop) {
        k1_bucket<<<NB * 32, 256, 0, stream>>>(
            posv, posh, tokv2, goff, tokh, cntv, cnth, gbase, AfH, AfL,
            invden, NB * 32);
        for (int b = 0; b < NB; b++) {
            kden<<<8, 256, 0, stream>>>(posv, posh, invden, b);
            k2_convh<<<1024, 256, 0, stream>>>(x, tokv2, cntv, goff, AfH, AfL, B1, b);
            k3_convv<<<1024, 256, 0, stream>>>(tokh, cnth, AfH, AfL, B1, invden, out, b);
        }
    } else {
        k_naive<<<NB * NT, 256, 0, stream>>>(x, posv, posh, out);
    }
}

// Round 20
// 72.039 us; speedup vs baseline: 1.0775x; 1.0149x over previous
//
#include <hip/hip_runtime.h>
#include <hip/hip_bf16.h>

// Problem constants (fixed by setup_inputs): B=8, T=2048, D=1024, positions in [0,64).
#define NB 8
#define NT 2048
#define ND 1024
#define CAP 2048

typedef unsigned short ushort_t;
using short8 = __attribute__((ext_vector_type(8))) short;   // 8 bf16 (4 VGPR)
using f32x4  = __attribute__((ext_vector_type(4))) float;   // MFMA accum

__device__ __forceinline__ ushort_t f2bf(float f) {
    __hip_bfloat16 h = __float2bfloat16(f);
    return *reinterpret_cast<ushort_t*>(&h);
}
__device__ __forceinline__ float bf2f(ushort_t u) {
    unsigned int v = ((unsigned int)u) << 16;
    return __int_as_float((int)v);
}

// XCD-aware bijective block swizzle (neutral-to-positive, kept from r19).
__device__ __forceinline__ int xcd_swizzle() {
    int bid = (int)blockIdx.x;
    return (bid >> 3) + ((bid & 7) * ((int)gridDim.x >> 3));
}

// MFMA operand K-slot mapping for 16x16x32 bf16: k(g,i) = (i>>2)*16+4g+(i&3),
// g = lane>>4. Consistent on A-table (k1) and B-reads (k2/k3) -> any
// permutation error cancels over the reduction axis. C/D: col=lane&15,
// row=4*(lane>>4)+reg [HW-verified]. (Validated: rounds 13-19 absmax.)

// ---------------------------------------------------------------------------
// Workspace layout (byte offsets):
// ---------------------------------------------------------------------------
#define OFF_G2     256
#define OFF_AFH    768
#define OFF_AFL    8960
#define OFF_CNTV   17152
#define OFF_CNTH   19200
#define OFF_INVDEN 21248
#define OFF_GOFF   152320
#define OFF_TOKV   160512
#define OFF_TOKH   4354816
#define OFF_TOKV2  8549120
#define OFF_B1     12743424
#define B1_SLAB    ((size_t)64 * 64 * 1024 * 2)   // 8 MB per batch (bf16)

// Shared kden body: denominator table via LDS-atomic INTEGER histogram
// (deterministic) + two 64x64 mini-matmuls. g table computed locally.
__device__ __forceinline__ void kden_body(
    int kb, const int* __restrict__ posv, const int* __restrict__ posh,
    float* __restrict__ invden, int b0)
{
    int b   = b0 + (kb >> 3);
    int phg = kb & 7;
    int tid = threadIdx.x;

    __shared__ int   hist[64][64];
    __shared__ float g2s[128];
    __shared__ float tmp[64][8];

#pragma unroll
    for (int k = 0; k < 16; k++) ((int*)hist)[tid + (k << 8)] = 0;
    if (tid < 128) {
        int k = tid, r = k - 63;
        g2s[tid] = (k < 127) ? expf(-(float)(r * r) * (1.0f / 512.0f)) : 0.0f;
    }
    __syncthreads();
#pragma unroll
    for (int k = 0; k < 8; k++) {
        int t = (k << 8) + tid;
        atomicAdd(&hist[posv[b * NT + t]][posh[b * NT + t]], 1);
    }
    __syncthreads();
#pragma unroll
    for (int c = 0; c < 2; c++) {
        int cell = (c << 8) + tid;
        int j    = cell >> 3;
        int phl  = cell & 7;
        int ph   = (phg << 3) + phl;
        float s = 0.f;
        for (int k = 0; k < 64; k++)
            s += (float)hist[j][k] * g2s[63 + k - ph];
        tmp[j][phl] = s;
    }
    __syncthreads();
#pragma unroll
    for (int c = 0; c < 2; c++) {
        int cell = (c << 8) + tid;
        int pv   = cell >> 3;
        int phl  = cell & 7;
        int ph   = (phg << 3) + phl;
        float s = 0.f;
        for (int j = 0; j < 64; j++)
            s += g2s[63 + j - pv] * tmp[j][phl];
        invden[(b * 64 + pv) * 64 + ph] = 1.0f / s;
    }
}

// K1: deterministic bucket lists via wave ballot compaction; posv-axis list
// emitted directly grouped by ph>>4 (two-pass ballot counting-sort). Block 0
// builds the MFMA A-fragment tables; blocks >= nbkt run the kden body.
__global__ __launch_bounds__(256) void k1_bucket(
    const int* __restrict__ posv, const int* __restrict__ posh,
    int* __restrict__ tokv2, int4* __restrict__ goff,
    int* __restrict__ tokh,
    int* __restrict__ cntv, int* __restrict__ cnth,
    float* __restrict__ gbase, ushort_t* __restrict__ AfH,
    ushort_t* __restrict__ AfL, float* __restrict__ invden, int nbkt)
{
    if ((int)blockIdx.x >= nbkt) {            // fused kden blocks
        kden_body((int)blockIdx.x - nbkt, posv, posh, invden, 0);
        return;
    }

    int b    = blockIdx.x >> 5;
    int blk  = blockIdx.x & 31;
    int wave = threadIdx.x >> 6;
    int lane = threadIdx.x & 63;

    if (blockIdx.x == 0) {
        if (threadIdx.x < 192) {
            int k = (int)threadIdx.x - 64;
            float v = 0.0f;
            if (k >= 0 && k < 127) {
                int r = k - 63;
                v = expf(-(float)(r * r) * (1.0f / 512.0f));
            }
            gbase[threadIdx.x] = v;
        }
#pragma unroll
        for (int p = 0; p < 16; p++) {
            int pos = (p << 8) + (int)threadIdx.x;   // 0..4095
            int i   = pos & 7;
            int ln  = (pos >> 3) & 63;
            int ks  = (pos >> 9) & 1;
            int w   = pos >> 10;
            int q   = (w << 4) + (ln & 15);
            int k   = (ks << 5) + ((i >> 2) << 4) + ((ln >> 4) << 2) + (i & 3);
            int dlt = q - k;
            float g = expf(-(float)(dlt * dlt) * (1.0f / 512.0f));
            ushort_t hi = f2bf(g);
            AfH[pos] = hi;
            AfL[pos] = f2bf(g - bf2f(hi));
        }
    }

    int task   = blk * 4 + wave;              // 0..127
    int bucket = task & 63;
    int use_ph = task >> 6;
    int bkt    = b * 64 + bucket;

    // combined per-token meta: posv | posh<<16
    int comb[32];
#pragma unroll
    for (int k = 0; k < 32; k++) {
        int t = k * 64 + lane;
        comb[k] = posv[b * NT + t] | (posh[b * NT + t] << 16);
    }

    unsigned long long lmask = (1ull << lane) - 1ull;

    if (use_ph == 0) {
        // tokv2: tokens with posv==bucket, grouped by ph>>4 (stable order).
        int* dst = tokv2 + (size_t)bkt * CAP;
        int cg0 = 0, cg1 = 0, cg2 = 0, cg3 = 0;
#pragma unroll 4
        for (int k = 0; k < 32; k++) {
            bool hit = (comb[k] & 0xffff) == bucket;
            int grp = (comb[k] >> 20) & 3;
            cg0 += (int)__popcll(__ballot(hit && grp == 0));
            cg1 += (int)__popcll(__ballot(hit && grp == 1));
            cg2 += (int)__popcll(__ballot(hit && grp == 2));
            cg3 += (int)__popcll(__ballot(hit && grp == 3));
        }
        int s1 = cg0, s2 = cg0 + cg1, s3 = cg0 + cg1 + cg2;
        int tot = s3 + cg3;
        if (lane == 0) {
            goff[bkt] = make_int4(0, s1, s2, s3);
            cntv[bkt] = tot;
        }
        int c0 = 0, c1 = s1, c2 = s2, c3 = s3;
#pragma unroll 4
        for (int k = 0; k < 32; k++) {
            bool hit = (comb[k] & 0xffff) == bucket;
            int grp = (comb[k] >> 20) & 3;
            unsigned long long m0 = __ballot(hit && grp == 0);
            unsigned long long m1 = __ballot(hit && grp == 1);
            unsigned long long m2 = __ballot(hit && grp == 2);
            unsigned long long m3 = __ballot(hit && grp == 3);
            if (hit) {
                int p;
                if      (grp == 0) p = c0 + (int)__popcll(m0 & lmask);
                else if (grp == 1) p = c1 + (int)__popcll(m1 & lmask);
                else if (grp == 2) p = c2 + (int)__popcll(m2 & lmask);
                else               p = c3 + (int)__popcll(m3 & lmask);
                dst[p] = (k * 64 + lane) | (comb[k] & 0xffff0000);
            }
            c0 += (int)__popcll(m0); c1 += (int)__popcll(m1);
            c2 += (int)__popcll(m2); c3 += (int)__popcll(m3);
        }
    } else {
        // tokh: tokens with posh==bucket, packed t | posv<<16.
        int* dst = tokh + (size_t)bkt * CAP;
        int cursor = 0;
#pragma unroll 4
        for (int k = 0; k < 32; k++) {
            bool hit = ((comb[k] >> 16) == bucket);
            unsigned long long m = __ballot(hit);
            if (hit)
                dst[cursor + __popcll(m & lmask)] =
                    (k * 64 + lane) | ((comb[k] & 0xffff) << 16);
            cursor += (int)__popcll(m);
        }
        if (lane == 0) cnth[bkt] = cursor;
    }
}

// Standalone kden (loop path only).
__global__ __launch_bounds__(256) void kden(
    const int* __restrict__ posv, const int* __restrict__ posh,
    float* __restrict__ invden, int b0)
{
    kden_body((int)blockIdx.x, posv, posh, invden, b0);
}

// B-fragment load: 8 bf16 at k = ks*32 + {4g..4g+3, 16+4g..16+4g+3}, row n.
__device__ __forceinline__ short8 ldsBfrag(const ushort_t* rowp, int ks, int g4) {
    const ushort_t* p = rowp + (ks << 5) + g4;
    uint2 lo = *(const uint2*)(p);
    uint2 hi = *(const uint2*)(p + 16);
    uint4 pk; pk.x = lo.x; pk.y = lo.y; pk.z = hi.x; pk.w = hi.y;
    return __builtin_bit_cast(short8, pk);
}

// K2: h-conv via MFMA — round-20: prefetch DEPTH 16 (two 8-token batches
// issued before the LDS-zero barrier). ~35% of wave-groups have 9..16
// tokens; in r15-19 their second batch ran serial-after-barrier (~800cy
// exposed). P(group>16) ~ 1% -> phase A is now fully latency-hidden for
// essentially all waves. Rest identical to round-17/19 proven structure.
__global__ __launch_bounds__(256) void k2_convh(
    const float* __restrict__ x,
    const int* __restrict__ tokv2, const int* __restrict__ cntv,
    const int4* __restrict__ goff,
    const ushort_t* __restrict__ AfH, const ushort_t* __restrict__ AfL,
    ushort_t* __restrict__ B1, int b0)
{
    int ell  = xcd_swizzle();
    int pv   = ell & 63;
    int dc   = (ell >> 6) & 15;
    int b    = b0 + (ell >> 10);
    int tid  = threadIdx.x;
    int lane = tid & 63;
    int w    = tid >> 6;
    int d0   = dc << 6;

    __shared__ float ldsf[64 * 65];               // 16640 B union buffer
    float    (*S)[65]   = (float(*)[65])ldsf;     // fp32 accum  S[d][ph]
    ushort_t (*S16)[68] = (ushort_t(*)[68])ldsf;  // bf16 operand / output

    int bucket = (b << 6) + pv;
    int n = cntv[bucket];
    const int* toks = tokv2 + (size_t)bucket * CAP;
    const float* xb = x + (((size_t)b * NT) << 10) + d0 + lane;

    int4 go = goff[bucket];
    int gs = (w == 0) ? go.x : (w == 1) ? go.y : (w == 2) ? go.z : go.w;
    int ge = (w == 3) ? n   : (w == 0) ? go.y : (w == 1) ? go.z : go.w;

    // --- prefetch window 0: meta + first SIXTEEN gathers before zeroing ---
    int wn0 = ge - gs; if (wn0 < 0) wn0 = 0; if (wn0 > 64) wn0 = 64;
    int m0  = wn0 > 8 ? 8 : wn0;
    int m1  = wn0 > 8 ? (wn0 > 16 ? 8 : wn0 - 8) : 0;
    int pkv = (wn0 > 0) ? toks[gs + lane] : 0;
    int pk0[8], pk1[8]; float xv0[8], xv1[8];
#pragma unroll
    for (int j = 0; j < 8; j++) pk0[j] = __builtin_amdgcn_readlane(pkv, j);
#pragma unroll
    for (int j = 0; j < 8; j++)
        if (j < m0) xv0[j] = xb[(size_t)(pk0[j] & 0xffff) << 10];
#pragma unroll
    for (int j = 0; j < 8; j++) pk1[j] = __builtin_amdgcn_readlane(pkv, 8 + j);
#pragma unroll
    for (int j = 0; j < 8; j++)
        if (j < m1) xv1[j] = xb[(size_t)(pk1[j] & 0xffff) << 10];

    // A-fragments issued early too (L2-resident after first blocks).
    short8 ahi[2], alo[2];
#pragma unroll
    for (int ks = 0; ks < 2; ks++) {
        int idx = ((((w << 1) + ks) << 6) + lane) << 3;
        ahi[ks] = *(const short8*)(AfH + idx);
        alo[ks] = *(const short8*)(AfL + idx);
    }

    // zero S while the loads are in flight
#pragma unroll
    for (int k = 0; k < 17; k++) {
        int idx = (k << 8) + tid;
        if (idx < 64 * 65) ldsf[idx] = 0.f;
    }
    __syncthreads();

    // consume prefetched batches
#pragma unroll
    for (int j = 0; j < 8; j++)
        if (j < m0) S[lane][pk0[j] >> 16] += xv0[j];
#pragma unroll
    for (int j = 0; j < 8; j++)
        if (j < m1) S[lane][pk1[j] >> 16] += xv1[j];

    // rest of window 0 (rare: wave-group >16 tokens)
    for (int i = 16; i < wn0; i += 8) {
        int m = wn0 - i; if (m > 8) m = 8;
        int pk[8]; float xv[8];
#pragma unroll
        for (int j = 0; j < 8; j++) pk[j] = __builtin_amdgcn_readlane(pkv, i + j);
#pragma unroll
        for (int j = 0; j < 8; j++)
            if (j < m) xv[j] = xb[(size_t)(pk[j] & 0xffff) << 10];
#pragma unroll
        for (int j = 0; j < 8; j++)
            if (j < m) S[lane][pk[j] >> 16] += xv[j];
    }
    // windows 1.. (very rare: wave-group >64 tokens)
    for (int win = gs + 64; win < ge; win += 64) {
        int wn = ge - win; if (wn > 64) wn = 64;
        int pkw = toks[win + lane];
        for (int i = 0; i < wn; i += 8) {
            int m = wn - i; if (m > 8) m = 8;
            int pk[8]; float xv[8];
#pragma unroll
            for (int j = 0; j < 8; j++) pk[j] = __builtin_amdgcn_readlane(pkw, i + j);
#pragma unroll
            for (int j = 0; j < 8; j++)
                if (j < m) xv[j] = xb[(size_t)(pk[j] & 0xffff) << 10];
#pragma unroll
            for (int j = 0; j < 8; j++)
                if (j < m) S[lane][pk[j] >> 16] += xv[j];
        }
    }
    __syncthreads();

    // in-place fp32 -> bf16 convert (read to regs, barrier, aliased write)
    {
        int r  = tid & 63;
        int c0 = (tid >> 6) << 4;
        float vals[16];
#pragma unroll
        for (int c = 0; c < 16; c++) vals[c] = S[r][c0 + c];
        __syncthreads();
#pragma unroll
        for (int c = 0; c < 16; c++) S16[r][c0 + c] = f2bf(vals[c]);
    }
    __syncthreads();

    // MFMA: Y[q][d] = (Ghi + Glo) . S16
    int g4 = (lane >> 4) << 2;
    int qbase = (w << 4) + g4;

    f32x4 accs[4];
#pragma unroll
    for (int nt = 0; nt < 4; nt++) {
        const ushort_t* rowp = &S16[(nt << 4) + (lane & 15)][0];
        f32x4 a = {0.f, 0.f, 0.f, 0.f};
#pragma unroll
        for (int ks = 0; ks < 2; ks++) {
            short8 bf = ldsBfrag(rowp, ks, g4);
            a = __builtin_amdgcn_mfma_f32_16x16x32_bf16(ahi[ks], bf, a, 0, 0, 0);
            a = __builtin_amdgcn_mfma_f32_16x16x32_bf16(alo[ks], bf, a, 0, 0, 0);
        }
        accs[nt] = a;
    }
    __syncthreads();                   // all S16 B-fragment reads done

    // Park results (rows=q, cols=d_local), then coalesced store.
#pragma unroll
    for (int nt = 0; nt < 4; nt++)
#pragma unroll
        for (int reg = 0; reg < 4; reg++)
            S16[qbase + reg][(nt << 4) + (lane & 15)] = f2bf(accs[nt][reg]);
    __syncthreads();

    ushort_t* B1p = B1 + (((size_t)(b - b0)) << 22) + (((size_t)pv) << 10) + d0;
#pragma unroll
    for (int pass = 0; pass < 2; pass++) {
        int row = (pass << 5) + (tid >> 3);      // 32 rows per pass
        int col = (tid & 7) << 3;                // 8 ushorts per thread
        uint4 v = *(const uint4*)(&S16[row][col]);
        *reinterpret_cast<uint4*>(B1p + ((size_t)row << 16) + col) = v;
    }
}

// K3: v-conv via MFMA + token scatter (round-17 structure + XCD swizzle).
__global__ __launch_bounds__(256) void k3_convv(
    const int* __restrict__ tokh, const int* __restrict__ cnth,
    const ushort_t* __restrict__ AfH, const ushort_t* __restrict__ AfL,
    const ushort_t* __restrict__ B1, const float* __restrict__ invden,
    float* __restrict__ out, int b0)
{
    int ell  = xcd_swizzle();
    int ph   = ell & 63;
    int dc   = (ell >> 6) & 15;
    int b    = b0 + (ell >> 10);
    int tid  = threadIdx.x;
    int lane = tid & 63;
    int w    = tid >> 6;
    int d0   = dc << 6;

    int n = cnth[(b << 6) + ph];
    if (n == 0) return;               // uniform across block

    __shared__ float ldsf[64 * 65];              // 16640 B union buffer
    ushort_t (*u16)[68] = (ushort_t(*)[68])ldsf; // staged B1 column
    float    (*y)[65]   = (float(*)[65])ldsf;    // conv output

    const ushort_t* B1b = B1 + (((size_t)(b - b0)) << 22) + (((size_t)ph) << 16)
                        + d0 + lane;
#pragma unroll
    for (int it = 0; it < 16; it++) {
        int j = (w << 4) + it;
        u16[lane][j] = B1b[(size_t)j << 10];
    }
    __syncthreads();

    short8 ahi[2], alo[2];
#pragma unroll
    for (int ks = 0; ks < 2; ks++) {
        int idx = ((((w << 1) + ks) << 6) + lane) << 3;
        ahi[ks] = *(const short8*)(AfH + idx);
        alo[ks] = *(const short8*)(AfL + idx);
    }
    int g4 = (lane >> 4) << 2;
    int qbase = (w << 4) + g4;

    f32x4 accs[4];
#pragma unroll
    for (int nt = 0; nt < 4; nt++) {
        const ushort_t* rowp = &u16[(nt << 4) + (lane & 15)][0];
        f32x4 a = {0.f, 0.f, 0.f, 0.f};
#pragma unroll
        for (int ks = 0; ks < 2; ks++) {
            short8 bf = ldsBfrag(rowp, ks, g4);
            a = __builtin_amdgcn_mfma_f32_16x16x32_bf16(ahi[ks], bf, a, 0, 0, 0);
            a = __builtin_amdgcn_mfma_f32_16x16x32_bf16(alo[ks], bf, a, 0, 0, 0);
        }
        accs[nt] = a;
    }
    __syncthreads();                   // all u16 reads done before y writes

#pragma unroll
    for (int nt = 0; nt < 4; nt++)
#pragma unroll
        for (int reg = 0; reg < 4; reg++)
            y[qbase + reg][(nt << 4) + (lane & 15)] = accs[nt][reg];
    __syncthreads();

    const int* toks = tokh + ((size_t)((b << 6) + ph)) * CAP;
    float* outb = out + (((size_t)b * NT) << 10) + d0 + lane;
    const float* ivb = invden + ((b << 6) << 6) + ph;

    int nch = (n + 3) >> 2;
    for (int c = w; c < nch; c += 4) {
        int i0 = c << 2;
        int4 M = *(const int4*)(toks + i0);   // safe past n: ws mapped
        int pk[4];
        pk[0] = __builtin_amdgcn_readfirstlane(M.x);
        pk[1] = __builtin_amdgcn_readfirstlane(M.y);
        pk[2] = __builtin_amdgcn_readfirstlane(M.z);
        pk[3] = __builtin_amdgcn_readfirstlane(M.w);
#pragma unroll
        for (int j = 0; j < 4; j++) {
            if (i0 + j < n) {
                int t   = pk[j] & 0xffff;
                int pvt = pk[j] >> 16;
                float iv = ivb[pvt << 6];
                outb[(size_t)t << 10] = y[pvt][lane] * iv;
            }
        }
    }
}

// Safety-net fallback (no workspace needed): direct O(T^2 * D) attention.
__global__ __launch_bounds__(256) void k_naive(
    const float* __restrict__ x, const int* __restrict__ posv,
    const int* __restrict__ posh, float* __restrict__ out)
{
    int t   = blockIdx.x & (NT - 1);
    int b   = blockIdx.x >> 11;
    int tid = threadIdx.x;

    __shared__ float s_w[NT];
    __shared__ float s_red[256];

    int pvt = posv[b * NT + t];
    int pht = posh[b * NT + t];

    float dsum = 0.0f;
    for (int s = tid; s < NT; s += 256) {
        int dv = pvt - posv[b * NT + s];
        int dh = pht - posh[b * NT + s];
        float w = expf(-(float)(dv * dv + dh * dh) * (1.0f / 512.0f));
        s_w[s] = w;
        dsum += w;
    }
    s_red[tid] = dsum;
    __syncthreads();
    for (int off = 128; off > 0; off >>= 1) {
        if (tid < off) s_red[tid] += s_red[tid + off];
        __syncthreads();
    }
    float inv = 1.0f / s_red[0];

    float a0 = 0.f, a1 = 0.f, a2 = 0.f, a3 = 0.f;
    for (int s = 0; s < NT; s++) {
        float w = s_w[s];
        const float* xr = x + (((size_t)(b * NT + s)) << 10);
        a0 = fmaf(w, xr[tid + 0],   a0);
        a1 = fmaf(w, xr[tid + 256], a1);
        a2 = fmaf(w, xr[tid + 512], a2);
        a3 = fmaf(w, xr[tid + 768], a3);
    }
    size_t ob = (((size_t)(b * NT + t)) << 10) + tid;
    out[ob + 0]   = a0 * inv;
    out[ob + 256] = a1 * inv;
    out[ob + 512] = a2 * inv;
    out[ob + 768] = a3 * inv;
}

extern "C" void kernel_launch(void* const* d_in, const int* in_sizes, int n_in,
                              void* d_out, int out_size, void* d_ws, size_t ws_size,
                              hipStream_t stream) {
    const float* x    = (const float*)d_in[0];
    const int*   posv = (const int*)d_in[1];
    const int*   posh = (const int*)d_in[2];
    float*       out  = (float*)d_out;

    char* ws = (char*)d_ws;
    float*    gbase  = (float*)ws;
    ushort_t* AfH    = (ushort_t*)(ws + OFF_AFH);
    ushort_t* AfL    = (ushort_t*)(ws + OFF_AFL);
    int*      cntv   = (int*)(ws + OFF_CNTV);
    int*      cnth   = (int*)(ws + OFF_CNTH);
    float*    invden = (float*)(ws + OFF_INVDEN);
    int4*     goff   = (int4*)(ws + OFF_GOFF);
    int*      tokh   = (int*)(ws + OFF_TOKH);
    int*      tokv2  = (int*)(ws + OFF_TOKV2);
    ushort_t* B1     = (ushort_t*)(ws + OFF_B1);

    const size_t needFull = (size_t)OFF_B1 + (size_t)NB * B1_SLAB;   // ~80 MB
    const size_t needLoop = (size_t)OFF_B1 + B1_SLAB;                // ~21 MB

    if (ws_size >= needFull) {
        // k1 (256 bucket blocks, emits grouped tokv2 directly) + fused kden
        k1_bucket<<<NB * 32 + NB * 8, 256, 0, stream>>>(
            posv, posh, tokv2, goff, tokh, cntv, cnth, gbase, AfH, AfL,
            invden, NB * 32);
        k2_convh<<<NB * 1024, 256, 0, stream>>>(x, tokv2, cntv, goff, AfH, AfL, B1, 0);
        k3_convv<<<NB * 1024, 256, 0, stream>>>(tokh, cnth, AfH, AfL, B1, invden, out, 0);
    } else if (ws_size >= needLoop) {
        k1_bucket<<<NB * 32, 256, 0, stream>>>(
            posv, posh, tokv2, goff, tokh, cntv, cnth, gbase, AfH, AfL,
            invden, NB * 32);
        for (int b = 0; b < NB; b++) {
            kden<<<8, 256, 0, stream>>>(posv, posh, invden, b);
            k2_convh<<<1024, 256, 0, stream>>>(x, tokv2, cntv, goff, AfH, AfL, B1, b);
            k3_convv<<<1024, 256, 0, stream>>>(tokh, cnth, AfH, AfL, B1, invden, out, b);
        }
    } else {
        k_naive<<<NB * NT, 256, 0, stream>>>(x, posv, posh, out);
    }
}

// Round 21
// 71.886 us; speedup vs baseline: 1.0798x; 1.0021x over previous
//
#include <hip/hip_runtime.h>
#include <hip/hip_bf16.h>

// Problem constants (fixed by setup_inputs): B=8, T=2048, D=1024, positions in [0,64).
#define NB 8
#define NT 2048
#define ND 1024
#define CAP 2048

typedef unsigned short ushort_t;
using short8 = __attribute__((ext_vector_type(8))) short;   // 8 bf16 (4 VGPR)
using f32x4  = __attribute__((ext_vector_type(4))) float;   // MFMA accum

__device__ __forceinline__ ushort_t f2bf(float f) {
    __hip_bfloat16 h = __float2bfloat16(f);
    return *reinterpret_cast<ushort_t*>(&h);
}
__device__ __forceinline__ float bf2f(ushort_t u) {
    unsigned int v = ((unsigned int)u) << 16;
    return __int_as_float((int)v);
}

// XCD-aware bijective block swizzle: consecutive LOGICAL ids land on the
// same XCD and run temporally adjacent.
__device__ __forceinline__ int xcd_swizzle() {
    int bid = (int)blockIdx.x;
    return (bid >> 3) + ((bid & 7) * ((int)gridDim.x >> 3));
}

// MFMA operand K-slot mapping for 16x16x32 bf16: k(g,i) = (i>>2)*16+4g+(i&3),
// g = lane>>4. Consistent on A-table (k1) and B-reads (k2/k3) -> any
// permutation error cancels over the reduction axis. C/D: col=lane&15,
// row=4*(lane>>4)+reg [HW-verified]. (Validated: rounds 13-20 absmax.)

// ---------------------------------------------------------------------------
// Workspace layout (byte offsets):
// ---------------------------------------------------------------------------
#define OFF_G2     256
#define OFF_AFH    768
#define OFF_AFL    8960
#define OFF_CNTV   17152
#define OFF_CNTH   19200
#define OFF_INVDEN 21248
#define OFF_GOFF   152320
#define OFF_TOKV   160512
#define OFF_TOKH   4354816
#define OFF_TOKV2  8549120
#define OFF_B1     12743424
#define B1_SLAB    ((size_t)64 * 64 * 1024 * 2)   // 8 MB per batch (bf16)

// Shared kden body: denominator table via LDS-atomic INTEGER histogram
// (deterministic) + two 64x64 mini-matmuls. g table computed locally.
__device__ __forceinline__ void kden_body(
    int kb, const int* __restrict__ posv, const int* __restrict__ posh,
    float* __restrict__ invden, int b0)
{
    int b   = b0 + (kb >> 3);
    int phg = kb & 7;
    int tid = threadIdx.x;

    __shared__ int   hist[64][64];
    __shared__ float g2s[128];
    __shared__ float tmp[64][8];

#pragma unroll
    for (int k = 0; k < 16; k++) ((int*)hist)[tid + (k << 8)] = 0;
    if (tid < 128) {
        int k = tid, r = k - 63;
        g2s[tid] = (k < 127) ? expf(-(float)(r * r) * (1.0f / 512.0f)) : 0.0f;
    }
    __syncthreads();
#pragma unroll
    for (int k = 0; k < 8; k++) {
        int t = (k << 8) + tid;
        atomicAdd(&hist[posv[b * NT + t]][posh[b * NT + t]], 1);
    }
    __syncthreads();
#pragma unroll
    for (int c = 0; c < 2; c++) {
        int cell = (c << 8) + tid;
        int j    = cell >> 3;
        int phl  = cell & 7;
        int ph   = (phg << 3) + phl;
        float s = 0.f;
        for (int k = 0; k < 64; k++)
            s += (float)hist[j][k] * g2s[63 + k - ph];
        tmp[j][phl] = s;
    }
    __syncthreads();
#pragma unroll
    for (int c = 0; c < 2; c++) {
        int cell = (c << 8) + tid;
        int pv   = cell >> 3;
        int phl  = cell & 7;
        int ph   = (phg << 3) + phl;
        float s = 0.f;
        for (int j = 0; j < 64; j++)
            s += g2s[63 + j - pv] * tmp[j][phl];
        invden[(b * 64 + pv) * 64 + ph] = 1.0f / s;
    }
}

// K1: deterministic bucket lists via wave ballot compaction; posv-axis list
// emitted directly grouped by ph>>4 (two-pass ballot counting-sort). Block 0
// builds the MFMA A-fragment tables; blocks >= nbkt run the kden body.
__global__ __launch_bounds__(256) void k1_bucket(
    const int* __restrict__ posv, const int* __restrict__ posh,
    int* __restrict__ tokv2, int4* __restrict__ goff,
    int* __restrict__ tokh,
    int* __restrict__ cntv, int* __restrict__ cnth,
    float* __restrict__ gbase, ushort_t* __restrict__ AfH,
    ushort_t* __restrict__ AfL, float* __restrict__ invden, int nbkt)
{
    if ((int)blockIdx.x >= nbkt) {            // fused kden blocks
        kden_body((int)blockIdx.x - nbkt, posv, posh, invden, 0);
        return;
    }

    int b    = blockIdx.x >> 5;
    int blk  = blockIdx.x & 31;
    int wave = threadIdx.x >> 6;
    int lane = threadIdx.x & 63;

    if (blockIdx.x == 0) {
        if (threadIdx.x < 192) {
            int k = (int)threadIdx.x - 64;
            float v = 0.0f;
            if (k >= 0 && k < 127) {
                int r = k - 63;
                v = expf(-(float)(r * r) * (1.0f / 512.0f));
            }
            gbase[threadIdx.x] = v;
        }
#pragma unroll
        for (int p = 0; p < 16; p++) {
            int pos = (p << 8) + (int)threadIdx.x;   // 0..4095
            int i   = pos & 7;
            int ln  = (pos >> 3) & 63;
            int ks  = (pos >> 9) & 1;
            int w   = pos >> 10;
            int q   = (w << 4) + (ln & 15);
            int k   = (ks << 5) + ((i >> 2) << 4) + ((ln >> 4) << 2) + (i & 3);
            int dlt = q - k;
            float g = expf(-(float)(dlt * dlt) * (1.0f / 512.0f));
            ushort_t hi = f2bf(g);
            AfH[pos] = hi;
            AfL[pos] = f2bf(g - bf2f(hi));
        }
    }

    int task   = blk * 4 + wave;              // 0..127
    int bucket = task & 63;
    int use_ph = task >> 6;
    int bkt    = b * 64 + bucket;

    // combined per-token meta: posv | posh<<16
    int comb[32];
#pragma unroll
    for (int k = 0; k < 32; k++) {
        int t = k * 64 + lane;
        comb[k] = posv[b * NT + t] | (posh[b * NT + t] << 16);
    }

    unsigned long long lmask = (1ull << lane) - 1ull;

    if (use_ph == 0) {
        // tokv2: tokens with posv==bucket, grouped by ph>>4 (stable order).
        int* dst = tokv2 + (size_t)bkt * CAP;
        int cg0 = 0, cg1 = 0, cg2 = 0, cg3 = 0;
#pragma unroll 4
        for (int k = 0; k < 32; k++) {
            bool hit = (comb[k] & 0xffff) == bucket;
            int grp = (comb[k] >> 20) & 3;
            cg0 += (int)__popcll(__ballot(hit && grp == 0));
            cg1 += (int)__popcll(__ballot(hit && grp == 1));
            cg2 += (int)__popcll(__ballot(hit && grp == 2));
            cg3 += (int)__popcll(__ballot(hit && grp == 3));
        }
        int s1 = cg0, s2 = cg0 + cg1, s3 = cg0 + cg1 + cg2;
        int tot = s3 + cg3;
        if (lane == 0) {
            goff[bkt] = make_int4(0, s1, s2, s3);
            cntv[bkt] = tot;
        }
        int c0 = 0, c1 = s1, c2 = s2, c3 = s3;
#pragma unroll 4
        for (int k = 0; k < 32; k++) {
            bool hit = (comb[k] & 0xffff) == bucket;
            int grp = (comb[k] >> 20) & 3;
            unsigned long long m0 = __ballot(hit && grp == 0);
            unsigned long long m1 = __ballot(hit && grp == 1);
            unsigned long long m2 = __ballot(hit && grp == 2);
            unsigned long long m3 = __ballot(hit && grp == 3);
            if (hit) {
                int p;
                if      (grp == 0) p = c0 + (int)__popcll(m0 & lmask);
                else if (grp == 1) p = c1 + (int)__popcll(m1 & lmask);
                else if (grp == 2) p = c2 + (int)__popcll(m2 & lmask);
                else               p = c3 + (int)__popcll(m3 & lmask);
                dst[p] = (k * 64 + lane) | (comb[k] & 0xffff0000);
            }
            c0 += (int)__popcll(m0); c1 += (int)__popcll(m1);
            c2 += (int)__popcll(m2); c3 += (int)__popcll(m3);
        }
    } else {
        // tokh: tokens with posh==bucket, packed t | posv<<16.
        int* dst = tokh + (size_t)bkt * CAP;
        int cursor = 0;
#pragma unroll 4
        for (int k = 0; k < 32; k++) {
            bool hit = ((comb[k] >> 16) == bucket);
            unsigned long long m = __ballot(hit);
            if (hit)
                dst[cursor + __popcll(m & lmask)] =
                    (k * 64 + lane) | ((comb[k] & 0xffff) << 16);
            cursor += (int)__popcll(m);
        }
        if (lane == 0) cnth[bkt] = cursor;
    }
}

// Standalone kden (loop path only).
__global__ __launch_bounds__(256) void kden(
    const int* __restrict__ posv, const int* __restrict__ posh,
    float* __restrict__ invden, int b0)
{
    kden_body((int)blockIdx.x, posv, posh, invden, b0);
}

// B-fragment load: 8 bf16 at k = ks*32 + {4g..4g+3, 16+4g..16+4g+3}, row n.
__device__ __forceinline__ short8 ldsBfrag(const ushort_t* rowp, int ks, int g4) {
    const ushort_t* p = rowp + (ks << 5) + g4;
    uint2 lo = *(const uint2*)(p);
    uint2 hi = *(const uint2*)(p + 16);
    uint4 pk; pk.x = lo.x; pk.y = lo.y; pk.z = hi.x; pk.w = hi.y;
    return __builtin_bit_cast(short8, pk);
}

// K2: h-conv via MFMA — round-21: DC-FASTEST block decode. The 16 dc
// blocks of one (b,pv) bucket are now consecutive logical ids -> same XCD,
// temporally adjacent -> they read ADJACENT 256B slices of the SAME token
// rows, merging into full 4KB row streams in L2/DRAM (k2 was pinned at
// 2.3 TB/s = isolated-256B effective ceiling across 7 structural variants).
// Kernel body otherwise identical to round-20 (prefetch-16 + union LDS).
__global__ __launch_bounds__(256) void k2_convh(
    const float* __restrict__ x,
    const int* __restrict__ tokv2, const int* __restrict__ cntv,
    const int4* __restrict__ goff,
    const ushort_t* __restrict__ AfH, const ushort_t* __restrict__ AfL,
    ushort_t* __restrict__ B1, int b0)
{
    int ell  = xcd_swizzle();
    int dc   = ell & 15;                 // fastest: row-slice coalescing
    int pv   = (ell >> 4) & 63;
    int b    = b0 + (ell >> 10);
    int tid  = threadIdx.x;
    int lane = tid & 63;
    int w    = tid >> 6;
    int d0   = dc << 6;

    __shared__ float ldsf[64 * 65];               // 16640 B union buffer
    float    (*S)[65]   = (float(*)[65])ldsf;     // fp32 accum  S[d][ph]
    ushort_t (*S16)[68] = (ushort_t(*)[68])ldsf;  // bf16 operand / output

    int bucket = (b << 6) + pv;
    int n = cntv[bucket];
    const int* toks = tokv2 + (size_t)bucket * CAP;
    const float* xb = x + (((size_t)b * NT) << 10) + d0 + lane;

    int4 go = goff[bucket];
    int gs = (w == 0) ? go.x : (w == 1) ? go.y : (w == 2) ? go.z : go.w;
    int ge = (w == 3) ? n   : (w == 0) ? go.y : (w == 1) ? go.z : go.w;

    // --- prefetch window 0: meta + first SIXTEEN gathers before zeroing ---
    int wn0 = ge - gs; if (wn0 < 0) wn0 = 0; if (wn0 > 64) wn0 = 64;
    int m0  = wn0 > 8 ? 8 : wn0;
    int m1  = wn0 > 8 ? (wn0 > 16 ? 8 : wn0 - 8) : 0;
    int pkv = (wn0 > 0) ? toks[gs + lane] : 0;
    int pk0[8], pk1[8]; float xv0[8], xv1[8];
#pragma unroll
    for (int j = 0; j < 8; j++) pk0[j] = __builtin_amdgcn_readlane(pkv, j);
#pragma unroll
    for (int j = 0; j < 8; j++)
        if (j < m0) xv0[j] = xb[(size_t)(pk0[j] & 0xffff) << 10];
#pragma unroll
    for (int j = 0; j < 8; j++) pk1[j] = __builtin_amdgcn_readlane(pkv, 8 + j);
#pragma unroll
    for (int j = 0; j < 8; j++)
        if (j < m1) xv1[j] = xb[(size_t)(pk1[j] & 0xffff) << 10];

    // A-fragments issued early too (L2-resident after first blocks).
    short8 ahi[2], alo[2];
#pragma unroll
    for (int ks = 0; ks < 2; ks++) {
        int idx = ((((w << 1) + ks) << 6) + lane) << 3;
        ahi[ks] = *(const short8*)(AfH + idx);
        alo[ks] = *(const short8*)(AfL + idx);
    }

    // zero S while the loads are in flight
#pragma unroll
    for (int k = 0; k < 17; k++) {
        int idx = (k << 8) + tid;
        if (idx < 64 * 65) ldsf[idx] = 0.f;
    }
    __syncthreads();

    // consume prefetched batches
#pragma unroll
    for (int j = 0; j < 8; j++)
        if (j < m0) S[lane][pk0[j] >> 16] += xv0[j];
#pragma unroll
    for (int j = 0; j < 8; j++)
        if (j < m1) S[lane][pk1[j] >> 16] += xv1[j];

    // rest of window 0 (rare: wave-group >16 tokens)
    for (int i = 16; i < wn0; i += 8) {
        int m = wn0 - i; if (m > 8) m = 8;
        int pk[8]; float xv[8];
#pragma unroll
        for (int j = 0; j < 8; j++) pk[j] = __builtin_amdgcn_readlane(pkv, i + j);
#pragma unroll
        for (int j = 0; j < 8; j++)
            if (j < m) xv[j] = xb[(size_t)(pk[j] & 0xffff) << 10];
#pragma unroll
        for (int j = 0; j < 8; j++)
            if (j < m) S[lane][pk[j] >> 16] += xv[j];
    }
    // windows 1.. (very rare: wave-group >64 tokens)
    for (int win = gs + 64; win < ge; win += 64) {
        int wn = ge - win; if (wn > 64) wn = 64;
        int pkw = toks[win + lane];
        for (int i = 0; i < wn; i += 8) {
            int m = wn - i; if (m > 8) m = 8;
            int pk[8]; float xv[8];
#pragma unroll
            for (int j = 0; j < 8; j++) pk[j] = __builtin_amdgcn_readlane(pkw, i + j);
#pragma unroll
            for (int j = 0; j < 8; j++)
                if (j < m) xv[j] = xb[(size_t)(pk[j] & 0xffff) << 10];
#pragma unroll
            for (int j = 0; j < 8; j++)
                if (j < m) S[lane][pk[j] >> 16] += xv[j];
        }
    }
    __syncthreads();

    // in-place fp32 -> bf16 convert (read to regs, barrier, aliased write)
    {
        int r  = tid & 63;
        int c0 = (tid >> 6) << 4;
        float vals[16];
#pragma unroll
        for (int c = 0; c < 16; c++) vals[c] = S[r][c0 + c];
        __syncthreads();
#pragma unroll
        for (int c = 0; c < 16; c++) S16[r][c0 + c] = f2bf(vals[c]);
    }
    __syncthreads();

    // MFMA: Y[q][d] = (Ghi + Glo) . S16
    int g4 = (lane >> 4) << 2;
    int qbase = (w << 4) + g4;

    f32x4 accs[4];
#pragma unroll
    for (int nt = 0; nt < 4; nt++) {
        const ushort_t* rowp = &S16[(nt << 4) + (lane & 15)][0];
        f32x4 a = {0.f, 0.f, 0.f, 0.f};
#pragma unroll
        for (int ks = 0; ks < 2; ks++) {
            short8 bf = ldsBfrag(rowp, ks, g4);
            a = __builtin_amdgcn_mfma_f32_16x16x32_bf16(ahi[ks], bf, a, 0, 0, 0);
            a = __builtin_amdgcn_mfma_f32_16x16x32_bf16(alo[ks], bf, a, 0, 0, 0);
        }
        accs[nt] = a;
    }
    __syncthreads();                   // all S16 B-fragment reads done

    // Park results (rows=q, cols=d_local), then coalesced store.
#pragma unroll
    for (int nt = 0; nt < 4; nt++)
#pragma unroll
        for (int reg = 0; reg < 4; reg++)
            S16[qbase + reg][(nt << 4) + (lane & 15)] = f2bf(accs[nt][reg]);
    __syncthreads();

    ushort_t* B1p = B1 + (((size_t)(b - b0)) << 22) + (((size_t)pv) << 10) + d0;
#pragma unroll
    for (int pass = 0; pass < 2; pass++) {
        int row = (pass << 5) + (tid >> 3);      // 32 rows per pass
        int col = (tid & 7) << 3;                // 8 ushorts per thread
        uint4 v = *(const uint4*)(&S16[row][col]);
        *reinterpret_cast<uint4*>(B1p + ((size_t)row << 16) + col) = v;
    }
}

// K3: v-conv via MFMA + token scatter — dc-fastest decode (same reasoning:
// 16 dc blocks of one ph read adjacent slices of the same B1 rows).
__global__ __launch_bounds__(256) void k3_convv(
    const int* __restrict__ tokh, const int* __restrict__ cnth,
    const ushort_t* __restrict__ AfH, const ushort_t* __restrict__ AfL,
    const ushort_t* __restrict__ B1, const float* __restrict__ invden,
    float* __restrict__ out, int b0)
{
    int ell  = xcd_swizzle();
    int dc   = ell & 15;
    int ph   = (ell >> 4) & 63;
    int b    = b0 + (ell >> 10);
    int tid  = threadIdx.x;
    int lane = tid & 63;
    int w    = tid >> 6;
    int d0   = dc << 6;

    int n = cnth[(b << 6) + ph];
    if (n == 0) return;               // uniform across block

    __shared__ float ldsf[64 * 65];              // 16640 B union buffer
    ushort_t (*u16)[68] = (ushort_t(*)[68])ldsf; // staged B1 column
    float    (*y)[65]   = (float(*)[65])ldsf;    // conv output

    const ushort_t* B1b = B1 + (((size_t)(b - b0)) << 22) + (((size_t)ph) << 16)
                        + d0 + lane;
#pragma unroll
    for (int it = 0; it < 16; it++) {
        int j = (w << 4) + it;
        u16[lane][j] = B1b[(size_t)j << 10];
    }
    __syncthreads();

    short8 ahi[2], alo[2];
#pragma unroll
    for (int ks = 0; ks < 2; ks++) {
        int idx = ((((w << 1) + ks) << 6) + lane) << 3;
        ahi[ks] = *(const short8*)(AfH + idx);
        alo[ks] = *(const short8*)(AfL + idx);
    }
    int g4 = (lane >> 4) << 2;
    int qbase = (w << 4) + g4;

    f32x4 accs[4];
#pragma unroll
    for (int nt = 0; nt < 4; nt++) {
        const ushort_t* rowp = &u16[(nt << 4) + (lane & 15)][0];
        f32x4 a = {0.f, 0.f, 0.f, 0.f};
#pragma unroll
        for (int ks = 0; ks < 2; ks++) {
            short8 bf = ldsBfrag(rowp, ks, g4);
            a = __builtin_amdgcn_mfma_f32_16x16x32_bf16(ahi[ks], bf, a, 0, 0, 0);
            a = __builtin_amdgcn_mfma_f32_16x16x32_bf16(alo[ks], bf, a, 0, 0, 0);
        }
        accs[nt] = a;
    }
    __syncthreads();                   // all u16 reads done before y writes

#pragma unroll
    for (int nt = 0; nt < 4; nt++)
#pragma unroll
        for (int reg = 0; reg < 4; reg++)
            y[qbase + reg][(nt << 4) + (lane & 15)] = accs[nt][reg];
    __syncthreads();

    const int* toks = tokh + ((size_t)((b << 6) + ph)) * CAP;
    float* outb = out + (((size_t)b * NT) << 10) + d0 + lane;
    const float* ivb = invden + ((b << 6) << 6) + ph;

    int nch = (n + 3) >> 2;
    for (int c = w; c < nch; c += 4) {
        int i0 = c << 2;
        int4 M = *(const int4*)(toks + i0);   // safe past n: ws mapped
        int pk[4];
        pk[0] = __builtin_amdgcn_readfirstlane(M.x);
        pk[1] = __builtin_amdgcn_readfirstlane(M.y);
        pk[2] = __builtin_amdgcn_readfirstlane(M.z);
        pk[3] = __builtin_amdgcn_readfirstlane(M.w);
#pragma unroll
        for (int j = 0; j < 4; j++) {
            if (i0 + j < n) {
                int t   = pk[j] & 0xffff;
                int pvt = pk[j] >> 16;
                float iv = ivb[pvt << 6];
                outb[(size_t)t << 10] = y[pvt][lane] * iv;
            }
        }
    }
}

// Safety-net fallback (no workspace needed): direct O(T^2 * D) attention.
__global__ __launch_bounds__(256) void k_naive(
    const float* __restrict__ x, const int* __restrict__ posv,
    const int* __restrict__ posh, float* __restrict__ out)
{
    int t   = blockIdx.x & (NT - 1);
    int b   = blockIdx.x >> 11;
    int tid = threadIdx.x;

    __shared__ float s_w[NT];
    __shared__ float s_red[256];

    int pvt = posv[b * NT + t];
    int pht = posh[b * NT + t];

    float dsum = 0.0f;
    for (int s = tid; s < NT; s += 256) {
        int dv = pvt - posv[b * NT + s];
        int dh = pht - posh[b * NT + s];
        float w = expf(-(float)(dv * dv + dh * dh) * (1.0f / 512.0f));
        s_w[s] = w;
        dsum += w;
    }
    s_red[tid] = dsum;
    __syncthreads();
    for (int off = 128; off > 0; off >>= 1) {
        if (tid < off) s_red[tid] += s_red[tid + off];
        __syncthreads();
    }
    float inv = 1.0f / s_red[0];

    float a0 = 0.f, a1 = 0.f, a2 = 0.f, a3 = 0.f;
    for (int s = 0; s < NT; s++) {
        float w = s_w[s];
        const float* xr = x + (((size_t)(b * NT + s)) << 10);
        a0 = fmaf(w, xr[tid + 0],   a0);
        a1 = fmaf(w, xr[tid + 256], a1);
        a2 = fmaf(w, xr[tid + 512], a2);
        a3 = fmaf(w, xr[tid + 768], a3);
    }
    size_t ob = (((size_t)(b * NT + t)) << 10) + tid;
    out[ob + 0]   = a0 * inv;
    out[ob + 256] = a1 * inv;
    out[ob + 512] = a2 * inv;
    out[ob + 768] = a3 * inv;
}

extern "C" void kernel_launch(void* const* d_in, const int* in_sizes, int n_in,
                              void* d_out, int out_size, void* d_ws, size_t ws_size,
                              hipStream_t stream) {
    const float* x    = (const float*)d_in[0];
    const int*   posv = (const int*)d_in[1];
    const int*   posh = (const int*)d_in[2];
    float*       out  = (float*)d_out;

    char* ws = (char*)d_ws;
    float*    gbase  = (float*)ws;
    ushort_t* AfH    = (ushort_t*)(ws + OFF_AFH);
    ushort_t* AfL    = (ushort_t*)(ws + OFF_AFL);
    int*      cntv   = (int*)(ws + OFF_CNTV);
    int*      cnth   = (int*)(ws + OFF_CNTH);
    float*    invden = (float*)(ws + OFF_INVDEN);
    int4*     goff   = (int4*)(ws + OFF_GOFF);
    int*      tokh   = (int*)(ws + OFF_TOKH);
    int*      tokv2  = (int*)(ws + OFF_TOKV2);
    ushort_t* B1     = (ushort_t*)(ws + OFF_B1);

    const size_t needFull = (size_t)OFF_B1 + (size_t)NB * B1_SLAB;   // ~80 MB
    const size_t needLoop = (size_t)OFF_B1 + B1_SLAB;                // ~21 MB

    if (ws_size >= needFull) {
        // k1 (256 bucket blocks, emits grouped tokv2 directly) + fused kden
        k1_bucket<<<NB * 32 + NB * 8, 256, 0, stream>>>(
            posv, posh, tokv2, goff, tokh, cntv, cnth, gbase, AfH, AfL,
            invden, NB * 32);
        k2_convh<<<NB * 1024, 256, 0, stream>>>(x, tokv2, cntv, goff, AfH, AfL, B1, 0);
        k3_convv<<<NB * 1024, 256, 0, stream>>>(tokh, cnth, AfH, AfL, B1, invden, out, 0);
    } else if (ws_size >= needLoop) {
        k1_bucket<<<NB * 32, 256, 0, stream>>>(
            posv, posh, tokv2, goff, tokh, cntv, cnth, gbase, AfH, AfL,
            invden, NB * 32);
        for (int b = 0; b < NB; b++) {
            kden<<<8, 256, 0, stream>>>(posv, posh, invden, b);
            k2_convh<<<1024, 256, 0, stream>>>(x, tokv2, cntv, goff, AfH, AfL, B1, b);
            k3_convv<<<1024, 256, 0, stream>>>(tokh, cnth, AfH, AfL, B1, invden, out, b);
        }
    } else {
        k_naive<<<NB * NT, 256, 0, stream>>>(x, posv, posh, out);
    }
}